// Round 11
// baseline (611.711 us; speedup 1.0000x reference)
//
#include <hip/hip_runtime.h>
#include <math.h>

#define KAPPA 0.9f
#define ST 68   // LDS row stride (64+4); 68%32=4 -> 2-way aliasing (free)
#define TN 16   // nodes per iter-kernel tile -> 1250 blocks -> ~4.9/CU

__device__ __forceinline__ float relu_f(float v) { return fmaxf(v, 0.0f); }

// ---------------- Wn_hat = KAPPA * Wn / max(||Wn||_F, 1) ----------------
__global__ __launch_bounds__(256) void wnhat_kernel(const float* __restrict__ Wn,
                                                    float* __restrict__ Wn_hat) {
  __shared__ float red[4];
  int t = threadIdx.x;
  float v[16];
  float s = 0.f;
#pragma unroll
  for (int j = 0; j < 16; ++j) { v[j] = Wn[t + 256 * j]; s += v[j] * v[j]; }
#pragma unroll
  for (int off = 32; off > 0; off >>= 1) s += __shfl_down(s, off, 64);
  if ((t & 63) == 0) red[t >> 6] = s;
  __syncthreads();
  float norm = sqrtf(red[0] + red[1] + red[2] + red[3]);
  float scale = KAPPA / fmaxf(norm, 1.0f);
#pragma unroll
  for (int j = 0; j < 16; ++j) Wn_hat[t + 256 * j] = v[j] * scale;
}

// ---------------- bias_n[n][h] = sum_k Om_n[h][k] * node_data[k][n] ----------------
__global__ __launch_bounds__(256) void bias_n_kernel(const float* __restrict__ node_data,
                                                     const float* __restrict__ Om_n,
                                                     float* __restrict__ bias_n, int N) {
  __shared__ float NdT[64][ST];  // [n][k]
  __shared__ float Om[64][ST];   // [h][k]
  int t = threadIdx.x;
  int n_base = blockIdx.x * 64;
#pragma unroll
  for (int j = 0; j < 16; ++j) {
    int f = t + 256 * j;
    int r = f >> 6, c = f & 63;
    float val = (n_base + c < N) ? node_data[(size_t)r * N + n_base + c] : 0.f;
    NdT[c][r] = val;
    Om[r][c] = Om_n[f];
  }
  __syncthreads();
  int ni = t & 15, h4 = (t >> 4) * 4;
  float acc[4][4] = {};
#pragma unroll 4
  for (int k = 0; k < 64; k += 4) {
    float4 a[4], w[4];
#pragma unroll
    for (int i = 0; i < 4; ++i) a[i] = *(const float4*)&NdT[ni + 16 * i][k];
#pragma unroll
    for (int j = 0; j < 4; ++j) w[j] = *(const float4*)&Om[h4 + j][k];
#pragma unroll
    for (int i = 0; i < 4; ++i)
#pragma unroll
      for (int j = 0; j < 4; ++j)
        acc[i][j] += a[i].x * w[j].x + a[i].y * w[j].y + a[i].z * w[j].z + a[i].w * w[j].w;
  }
#pragma unroll
  for (int i = 0; i < 4; ++i) {
    int n = n_base + ni + 16 * i;
    if (n < N) {
      float4 o = make_float4(acc[i][0], acc[i][1], acc[i][2], acc[i][3]);
      *(float4*)&bias_n[(size_t)n * 64 + h4] = o;
    }
  }
}

// ---------------- CSR build: histogram / scan / scatter ----------------
__global__ void hist_kernel(const int* __restrict__ H, int* __restrict__ count, int E) {
  int e = blockIdx.x * 256 + threadIdx.x;
  if (e < E) atomicAdd(&count[H[e]], 1);
}

__global__ __launch_bounds__(256) void scan_kernel(int* count, int* row_off, int* cursor,
                                                   int N, int E) {
  __shared__ int offs[256];
  __shared__ int sums[256];
  int t = threadIdx.x;
  int chunk = (N + 255) / 256;
  int lo = t * chunk, hi = min(lo + chunk, N);
  int s = 0;
  for (int n = lo; n < hi; ++n) s += count[n];
  sums[t] = s;
  __syncthreads();
  if (t == 0) {
    int run = 0;
    for (int i = 0; i < 256; ++i) { offs[i] = run; run += sums[i]; }
  }
  __syncthreads();
  int run = offs[t];
  for (int n = lo; n < hi; ++n) {
    int c = count[n];   // count and cursor may alias: read first
    row_off[n] = run;
    cursor[n] = run;
    run += c;
  }
  if (t == 0) row_off[N] = E;
}

__global__ void scatter_kernel(const int* __restrict__ H, const int* __restrict__ S,
                               const int* __restrict__ R, int* cursor,
                               int* __restrict__ Ss, int* __restrict__ Rs,
                               int* __restrict__ inv_perm, int E) {
  int e = blockIdx.x * 256 + threadIdx.x;
  if (e < E) {
    int h = H[e];
    int pos = atomicAdd(&cursor[h], 1);
    Ss[pos] = S[e];
    Rs[pos] = R[e];
    inv_perm[e] = pos;
  }
}

// ---------------- bias_s[inv_perm[e]][h] = sum_j Om_e[h][j] * Ra[j][e] ----------------
__global__ __launch_bounds__(256) void bias_build_kernel(const float* __restrict__ Ra,
                                                         const float* __restrict__ Om_e,
                                                         const int* __restrict__ inv_perm,
                                                         float* __restrict__ bias_s, int E) {
  __shared__ float OmT[64][36];  // [h][j]
  __shared__ float RaT[64][36];  // [e][j]
  int t = threadIdx.x;
  int e_base = blockIdx.x * 64;
#pragma unroll
  for (int j = 0; j < 8; ++j) {
    int f = t + 256 * j;  // 2048 = 64h x 32j
    int r = f >> 5, c = f & 31;
    OmT[r][c] = Om_e[f];
  }
#pragma unroll
  for (int j = 0; j < 8; ++j) {
    int f = t + 256 * j;  // 2048 = 32j x 64e
    int r = f >> 6, c = f & 63;
    int ee = e_base + c;
    RaT[c][r] = (ee < E) ? Ra[(size_t)r * E + ee] : 0.f;
  }
  __syncthreads();
  int ei = t & 15, h4 = (t >> 4) * 4;
  float acc[4][4] = {};
#pragma unroll 4
  for (int jj = 0; jj < 32; jj += 4) {
    float4 ra[4], om[4];
#pragma unroll
    for (int i = 0; i < 4; ++i) ra[i] = *(const float4*)&RaT[ei + 16 * i][jj];
#pragma unroll
    for (int j = 0; j < 4; ++j) om[j] = *(const float4*)&OmT[h4 + j][jj];
#pragma unroll
    for (int i = 0; i < 4; ++i)
#pragma unroll
      for (int j = 0; j < 4; ++j)
        acc[i][j] += ra[i].x * om[j].x + ra[i].y * om[j].y + ra[i].z * om[j].z +
                     ra[i].w * om[j].w;
  }
#pragma unroll
  for (int i = 0; i < 4; ++i) {
    int e = e_base + ei + 16 * i;
    if (e < E) {
      int p = inv_perm[e];
      float4 o = make_float4(acc[i][0], acc[i][1], acc[i][2], acc[i][3]);
      *(float4*)&bias_s[(size_t)p * 64 + h4] = o;
    }
  }
}

// ---------------- fused iteration kernel (TN=16 nodes/block, 256 threads) ----------
// Weights read directly from global (L1/L2-resident; identical for all blocks).
// LDS = Xsh+Ash ~ 8.7KB -> occupancy grid-limited at ~4.9 blocks/CU.
// FIRST: X==0 => skip X staging and Wn_hat@X term.
// LAST: also run the dense head (V0/V1); skip the Xout write.
template <int FIRST, int LAST>
__global__ __launch_bounds__(256) void iter_kernel(
    const float* __restrict__ X, const float* __restrict__ MS_in,
    const float* __restrict__ MR_in, const float* __restrict__ bias_s,
    const int* __restrict__ Ss, const int* __restrict__ Rs,
    const int* __restrict__ row_off, const float* __restrict__ bias_n,
    const float* __restrict__ Wn_hat, const float* __restrict__ Bm,
    const float* __restrict__ W_es, const float* __restrict__ W_er,
    const float* __restrict__ V0_w, const float* __restrict__ V0_b,
    const float* __restrict__ V1_w, const float* __restrict__ V1_b,
    float* __restrict__ Xout, float* __restrict__ MS_out,
    float* __restrict__ MR_out, float* __restrict__ head_out, int N) {
  __shared__ float Xsh[TN][ST], Ash[TN][ST];
  int t = threadIdx.x;
  int n_base = blockIdx.x * TN;
  int n16 = t >> 4;   // node slot 0..15
  int q16 = t & 15;   // 4-float chunk 0..15
  int nd = n_base + n16;
  bool ok = nd < N;
  if (!FIRST) {
    float4 xv = make_float4(0, 0, 0, 0);
    if (ok) xv = *(const float4*)&X[(size_t)nd * 64 + q16 * 4];
    *(float4*)&Xsh[n16][q16 * 4] = xv;
  }
  // agg phase: 16 threads per node, each handles 4 floats of the 64-wide row
  float4 a0 = make_float4(0, 0, 0, 0);
  if (ok) {
    int r0 = row_off[nd], r1 = row_off[nd + 1];
    for (int p = r0; p < r1; ++p) {
      float4 b0 = *(const float4*)&bias_s[(size_t)p * 64 + q16 * 4];
      if (FIRST) {
        a0.x += relu_f(b0.x); a0.y += relu_f(b0.y);
        a0.z += relu_f(b0.z); a0.w += relu_f(b0.w);
      } else {
        int s = Ss[p], r = Rs[p];
        float4 m0 = *(const float4*)&MS_in[(size_t)s * 64 + q16 * 4];
        float4 r0v = *(const float4*)&MR_in[(size_t)r * 64 + q16 * 4];
        a0.x += relu_f(m0.x + r0v.x + b0.x);
        a0.y += relu_f(m0.y + r0v.y + b0.y);
        a0.z += relu_f(m0.z + r0v.z + b0.z);
        a0.w += relu_f(m0.w + r0v.w + b0.w);
      }
    }
  }
  *(float4*)&Ash[n16][q16 * 4] = a0;
  __syncthreads();
  // phase A: acc = Wn_hat@X + Bm@agg ; row = ni, cols = h4..h4+3
  int ni = t & 15, h4 = (t >> 4) * 4;
  float acc[4] = {};
#pragma unroll 2
  for (int k = 0; k < 64; k += 4) {
    float4 xv, av;
    if (!FIRST) xv = *(const float4*)&Xsh[ni][k];
    av = *(const float4*)&Ash[ni][k];
    float4 wv[4], bv[4];
#pragma unroll
    for (int j = 0; j < 4; ++j) {
      if (!FIRST) wv[j] = *(const float4*)&Wn_hat[(size_t)(h4 + j) * 64 + k];
      bv[j] = *(const float4*)&Bm[(size_t)(h4 + j) * 64 + k];
    }
#pragma unroll
    for (int j = 0; j < 4; ++j) {
      float v = av.x * bv[j].x + av.y * bv[j].y + av.z * bv[j].z + av.w * bv[j].w;
      if (!FIRST)
        v += xv.x * wv[j].x + xv.y * wv[j].y + xv.z * wv[j].z + xv.w * wv[j].w;
      acc[j] += v;
    }
  }
  __syncthreads();  // phase-A reads of Xsh/Ash done
  // epilogue A: xnew = relu(acc + bias_n) -> Xsh (and Xout unless LAST)
  {
    int nn = n_base + ni;
    float4 bb = make_float4(0, 0, 0, 0);
    if (nn < N) bb = *(const float4*)&bias_n[(size_t)nn * 64 + h4];
    float x0 = relu_f(acc[0] + bb.x);
    float x1 = relu_f(acc[1] + bb.y);
    float x2 = relu_f(acc[2] + bb.z);
    float x3 = relu_f(acc[3] + bb.w);
    if (!LAST && nn < N)
      *(float4*)&Xout[(size_t)nn * 64 + h4] = make_float4(x0, x1, x2, x3);
    *(float4*)&Xsh[ni][h4] = make_float4(x0, x1, x2, x3);
  }
  __syncthreads();
  // phase B: MS = Wes@xnew, MR = Wer@xnew
  {
    float ma[4] = {}, ra[4] = {};
#pragma unroll 2
    for (int k = 0; k < 64; k += 4) {
      float4 xv = *(const float4*)&Xsh[ni][k];
      float4 ws[4], wr[4];
#pragma unroll
      for (int j = 0; j < 4; ++j) {
        ws[j] = *(const float4*)&W_es[(size_t)(h4 + j) * 64 + k];
        wr[j] = *(const float4*)&W_er[(size_t)(h4 + j) * 64 + k];
      }
#pragma unroll
      for (int j = 0; j < 4; ++j) {
        ma[j] += xv.x * ws[j].x + xv.y * ws[j].y + xv.z * ws[j].z + xv.w * ws[j].w;
        ra[j] += xv.x * wr[j].x + xv.y * wr[j].y + xv.z * wr[j].z + xv.w * wr[j].w;
      }
    }
    int nn = n_base + ni;
    if (nn < N) {
      *(float4*)&MS_out[(size_t)nn * 64 + h4] = make_float4(ma[0], ma[1], ma[2], ma[3]);
      *(float4*)&MR_out[(size_t)nn * 64 + h4] = make_float4(ra[0], ra[1], ra[2], ra[3]);
    }
  }
  if (LAST) {
    // phase C: c1 = xnew @ V0^T (registers; Xsh unchanged since phase B)
    float c1[4] = {};
#pragma unroll 2
    for (int k = 0; k < 64; k += 4) {
      float4 xv = *(const float4*)&Xsh[ni][k];
      float4 wv[4];
#pragma unroll
      for (int j = 0; j < 4; ++j) wv[j] = *(const float4*)&V0_w[(size_t)(h4 + j) * 64 + k];
#pragma unroll
      for (int j = 0; j < 4; ++j)
        c1[j] += xv.x * wv[j].x + xv.y * wv[j].y + xv.z * wv[j].z + xv.w * wv[j].w;
    }
    __syncthreads();  // phase-C reads of Xsh done
    // x1 = relu(c1 + b0) -> Xsh
    {
      float4 o;
      o.x = relu_f(c1[0] + V0_b[h4 + 0]);
      o.y = relu_f(c1[1] + V0_b[h4 + 1]);
      o.z = relu_f(c1[2] + V0_b[h4 + 2]);
      o.w = relu_f(c1[3] + V0_b[h4 + 3]);
      *(float4*)&Xsh[ni][h4] = o;
    }
    __syncthreads();
    // phase D: out = x1 @ V1^T + b1
    float c2[4] = {};
#pragma unroll 2
    for (int k = 0; k < 64; k += 4) {
      float4 xv = *(const float4*)&Xsh[ni][k];
      float4 wv[4];
#pragma unroll
      for (int j = 0; j < 4; ++j) wv[j] = *(const float4*)&V1_w[(size_t)(h4 + j) * 64 + k];
#pragma unroll
      for (int j = 0; j < 4; ++j)
        c2[j] += xv.x * wv[j].x + xv.y * wv[j].y + xv.z * wv[j].z + xv.w * wv[j].w;
    }
    int nn = n_base + ni;
    if (nn < N) {
      float4 o;
      o.x = c2[0] + V1_b[h4 + 0];
      o.y = c2[1] + V1_b[h4 + 1];
      o.z = c2[2] + V1_b[h4 + 2];
      o.w = c2[3] + V1_b[h4 + 3];
      *(float4*)&head_out[(size_t)nn * 64 + h4] = o;
    }
  }
}

// ---------------- final edge kernel: pure gather + Om@Ra bias + transpose ----------
// He_logits[h][e] = MS[S[e]][h] + MR[R[e]][h] + (Om_e@Ra)[h][e]
__global__ __launch_bounds__(256) void edge_final_kernel(
    const float* __restrict__ MS, const float* __restrict__ MR,
    const int* __restrict__ S, const int* __restrict__ R,
    const float* __restrict__ Om_e, const float* __restrict__ Ra,
    float* __restrict__ He_out, float* __restrict__ Hel_out, int E) {
  __shared__ float T[64][ST];     // [e][h] gather tile
  __shared__ float pool2[4608];   // OmT[64][36] + RaT[64][36]; later transpose (64*65)
  int t = threadIdx.x;
  int e_base = blockIdx.x * 64;
#pragma unroll
  for (int j = 0; j < 8; ++j) {
    int f = t + 256 * j;  // 2048 = 64h x 32j
    int r = f >> 5, c = f & 31;
    pool2[r * 36 + c] = Om_e[f];
  }
#pragma unroll
  for (int j = 0; j < 8; ++j) {
    int f = t + 256 * j;  // 2048 = 32j x 64e
    int r = f >> 6, c = f & 63;
    int e2 = e_base + c;
    pool2[2304 + c * 36 + r] = (e2 < E) ? Ra[(size_t)r * E + e2] : 0.f;
  }
  // gather MS[S]+MR[R] into T
  {
    int e = t >> 2, q = t & 3;
    int ee = e_base + e;
    int ec = (ee < E) ? ee : 0;
    int s = S[ec], r = R[ec];
    const float* mp = &MS[(size_t)s * 64 + q * 16];
    const float* rp = &MR[(size_t)r * 64 + q * 16];
#pragma unroll
    for (int c = 0; c < 4; ++c) {
      float4 mv = *(const float4*)(mp + 4 * c);
      float4 rv = *(const float4*)(rp + 4 * c);
      *(float4*)&T[e][q * 16 + 4 * c] =
          make_float4(mv.x + rv.x, mv.y + rv.y, mv.z + rv.z, mv.w + rv.w);
    }
  }
  __syncthreads();
  int ei = t & 15, h4 = (t >> 4) * 4;
  float acc[4][4] = {};
#pragma unroll 4
  for (int jj = 0; jj < 32; jj += 4) {
    float4 ra[4], om[4];
#pragma unroll
    for (int i = 0; i < 4; ++i)
      ra[i] = *(const float4*)&pool2[2304 + (ei + 16 * i) * 36 + jj];
#pragma unroll
    for (int j = 0; j < 4; ++j) om[j] = *(const float4*)&pool2[(h4 + j) * 36 + jj];
#pragma unroll
    for (int i = 0; i < 4; ++i)
#pragma unroll
      for (int j = 0; j < 4; ++j)
        acc[i][j] += ra[i].x * om[j].x + ra[i].y * om[j].y + ra[i].z * om[j].z +
                     ra[i].w * om[j].w;
  }
  // add gathered MS+MR
#pragma unroll
  for (int i = 0; i < 4; ++i) {
    float4 tv = *(const float4*)&T[ei + 16 * i][h4];
    acc[i][0] += tv.x;
    acc[i][1] += tv.y;
    acc[i][2] += tv.z;
    acc[i][3] += tv.w;
  }
  __syncthreads();  // done reading pool2 (OmT/RaT) and T
  // transpose via pool2 (stride 65 -> conflict-light column reads)
#pragma unroll
  for (int i = 0; i < 4; ++i)
#pragma unroll
    for (int j = 0; j < 4; ++j)
      pool2[(ei + 16 * i) * 65 + h4 + j] = acc[i][j];
  __syncthreads();
  {
    int e4 = (t & 15) * 4, h0 = t >> 4;
#pragma unroll
    for (int rep = 0; rep < 4; ++rep) {
      int h = h0 + 16 * rep;
      float4 v;
      v.x = pool2[(e4 + 0) * 65 + h];
      v.y = pool2[(e4 + 1) * 65 + h];
      v.z = pool2[(e4 + 2) * 65 + h];
      v.w = pool2[(e4 + 3) * 65 + h];
      size_t idx = (size_t)h * E + e_base + e4;
      if (e_base + e4 < E) {
        *(float4*)&Hel_out[idx] = v;
        float4 u = make_float4(relu_f(v.x), relu_f(v.y), relu_f(v.z), relu_f(v.w));
        *(float4*)&He_out[idx] = u;
      }
    }
  }
}

extern "C" void kernel_launch(void* const* d_in, const int* in_sizes, int n_in,
                              void* d_out, int out_size, void* d_ws, size_t ws_size,
                              hipStream_t stream) {
  const int* R = (const int*)d_in[0];
  const int* S = (const int*)d_in[1];
  const int* H = (const int*)d_in[2];
  const float* node_data = (const float*)d_in[3];
  const float* Ra = (const float*)d_in[4];
  const float* W_es = (const float*)d_in[5];
  const float* W_er = (const float*)d_in[6];
  const float* Om_e = (const float*)d_in[7];
  const float* Wn = (const float*)d_in[8];
  const float* Bm = (const float*)d_in[9];
  const float* Om_n = (const float*)d_in[10];
  const float* V0_w = (const float*)d_in[11];
  const float* V0_b = (const float*)d_in[12];
  const float* V1_w = (const float*)d_in[13];
  const float* V1_b = (const float*)d_in[14];
  const int E = in_sizes[0];
  const int N = in_sizes[3] / 64;
  const size_t N64 = (size_t)N * 64;

  float* ws = (float*)d_ws;
  float* Wn_hat = ws;                    // 4096
  float* bias_n = Wn_hat + 4096;         // N64
  float* X0 = bias_n + N64;              // N64
  float* X1p = X0 + N64;                 // N64
  float* MS_B = X1p + N64;               // N64 (odd-iter MS; final MS)
  float* MR_B = MS_B + N64;              // N64 (odd-iter MR; final MR)
  int* row_off = (int*)(MR_B + N64);     // N+1
  int* cursor = row_off + (N + 1);       // N (doubles as histogram)
  int* Ss = cursor + N;                  // E
  int* Rs = Ss + E;                      // E
  int* inv_perm = Rs + E;                // E

  float* out = (float*)d_out;
  float* out_x = out;                          // [N][64]
  float* out_He = out + N64;                   // [64][E]
  float* out_Hel = out_He + (size_t)64 * E;    // [64][E]
  float* bias_s = out_He;    // He region: sorted-bias scratch during iterations
  float* MS_A = out_Hel;     // Hel region: even-iter MS/MR (dead before edge_final)
  float* MR_A = out_Hel + N64;

  int nb_node = (N + 63) / 64;
  int nb_iter = (N + TN - 1) / TN;
  int nb_edge = (E + 63) / 64;
  int nb_flat = (E + 255) / 256;

  hipMemsetAsync(cursor, 0, (size_t)N * sizeof(int), stream);
  wnhat_kernel<<<1, 256, 0, stream>>>(Wn, Wn_hat);
  bias_n_kernel<<<nb_node, 256, 0, stream>>>(node_data, Om_n, bias_n, N);
  hist_kernel<<<nb_flat, 256, 0, stream>>>(H, cursor, E);
  scan_kernel<<<1, 256, 0, stream>>>(cursor, row_off, cursor, N, E);
  scatter_kernel<<<nb_flat, 256, 0, stream>>>(H, S, R, cursor, Ss, Rs, inv_perm, E);
  bias_build_kernel<<<nb_edge, 256, 0, stream>>>(Ra, Om_e, inv_perm, bias_s, E);

  float* Xa = X0;
  float* Xb = X1p;
  const float* msi = nullptr;
  const float* mri = nullptr;
  for (int it = 0; it < 8; ++it) {
    float* mso = (it & 1) ? MS_B : MS_A;
    float* mro = (it & 1) ? MR_B : MR_A;
    if (it == 0)
      iter_kernel<1, 0><<<nb_iter, 256, 0, stream>>>(
          Xa, nullptr, nullptr, bias_s, Ss, Rs, row_off, bias_n, Wn_hat, Bm, W_es, W_er,
          V0_w, V0_b, V1_w, V1_b, Xb, mso, mro, out_x, N);
    else if (it < 7)
      iter_kernel<0, 0><<<nb_iter, 256, 0, stream>>>(
          Xa, msi, mri, bias_s, Ss, Rs, row_off, bias_n, Wn_hat, Bm, W_es, W_er,
          V0_w, V0_b, V1_w, V1_b, Xb, mso, mro, out_x, N);
    else
      iter_kernel<0, 1><<<nb_iter, 256, 0, stream>>>(
          Xa, msi, mri, bias_s, Ss, Rs, row_off, bias_n, Wn_hat, Bm, W_es, W_er,
          V0_w, V0_b, V1_w, V1_b, Xb, mso, mro, out_x, N);
    msi = mso;
    mri = mro;
    float* tmp = Xa; Xa = Xb; Xb = tmp;
  }
  // it=7 (odd) wrote MS_B/MR_B in ws; He/Hel regions are free to write now.
  edge_final_kernel<<<nb_edge, 256, 0, stream>>>(MS_B, MR_B, S, R, Om_e, Ra,
                                                 out_He, out_Hel, E);
}

// Round 12
// 486.257 us; speedup vs baseline: 1.2580x; 1.2580x over previous
//
#include <hip/hip_runtime.h>
#include <math.h>

#define KAPPA 0.9f
#define ST 68   // LDS row stride (64+4); 68%32=4 -> 2-way aliasing (free)
#define TN 32   // nodes per iter-kernel tile (625 blocks)

typedef unsigned short u16;

__device__ __forceinline__ float relu_f(float v) { return fmaxf(v, 0.0f); }
__device__ __forceinline__ float bf_lo(unsigned u) { return __uint_as_float(u << 16); }
__device__ __forceinline__ float bf_hi(unsigned u) { return __uint_as_float(u & 0xFFFF0000u); }
__device__ __forceinline__ u16 f2bf(float x) {
  unsigned u = __float_as_uint(x);
  return (u16)((u + 0x7FFFu + ((u >> 16) & 1u)) >> 16);
}
__device__ __forceinline__ unsigned pack2(float a, float b) {
  return (unsigned)f2bf(a) | ((unsigned)f2bf(b) << 16);
}

// ---------------- Wn_hat = KAPPA * Wn / max(||Wn||_F, 1) ----------------
__global__ __launch_bounds__(256) void wnhat_kernel(const float* __restrict__ Wn,
                                                    float* __restrict__ Wn_hat) {
  __shared__ float red[4];
  int t = threadIdx.x;
  float v[16];
  float s = 0.f;
#pragma unroll
  for (int j = 0; j < 16; ++j) { v[j] = Wn[t + 256 * j]; s += v[j] * v[j]; }
#pragma unroll
  for (int off = 32; off > 0; off >>= 1) s += __shfl_down(s, off, 64);
  if ((t & 63) == 0) red[t >> 6] = s;
  __syncthreads();
  float norm = sqrtf(red[0] + red[1] + red[2] + red[3]);
  float scale = KAPPA / fmaxf(norm, 1.0f);
#pragma unroll
  for (int j = 0; j < 16; ++j) Wn_hat[t + 256 * j] = v[j] * scale;
}

// ---------------- bias_n[n][h] = sum_k Om_n[h][k] * node_data[k][n] ----------------
__global__ __launch_bounds__(256) void bias_n_kernel(const float* __restrict__ node_data,
                                                     const float* __restrict__ Om_n,
                                                     float* __restrict__ bias_n, int N) {
  __shared__ float NdT[64][ST];  // [n][k]
  __shared__ float Om[64][ST];   // [h][k]
  int t = threadIdx.x;
  int n_base = blockIdx.x * 64;
#pragma unroll
  for (int j = 0; j < 16; ++j) {
    int f = t + 256 * j;
    int r = f >> 6, c = f & 63;
    float val = (n_base + c < N) ? node_data[(size_t)r * N + n_base + c] : 0.f;
    NdT[c][r] = val;
    Om[r][c] = Om_n[f];
  }
  __syncthreads();
  int ni = t & 15, h4 = (t >> 4) * 4;
  float acc[4][4] = {};
#pragma unroll 4
  for (int k = 0; k < 64; k += 4) {
    float4 a[4], w[4];
#pragma unroll
    for (int i = 0; i < 4; ++i) a[i] = *(const float4*)&NdT[ni + 16 * i][k];
#pragma unroll
    for (int j = 0; j < 4; ++j) w[j] = *(const float4*)&Om[h4 + j][k];
#pragma unroll
    for (int i = 0; i < 4; ++i)
#pragma unroll
      for (int j = 0; j < 4; ++j)
        acc[i][j] += a[i].x * w[j].x + a[i].y * w[j].y + a[i].z * w[j].z + a[i].w * w[j].w;
  }
#pragma unroll
  for (int i = 0; i < 4; ++i) {
    int n = n_base + ni + 16 * i;
    if (n < N) {
      float4 o = make_float4(acc[i][0], acc[i][1], acc[i][2], acc[i][3]);
      *(float4*)&bias_n[(size_t)n * 64 + h4] = o;
    }
  }
}

// ---------------- CSR build: histogram / scan / scatter ----------------
__global__ void hist_kernel(const int* __restrict__ H, int* __restrict__ count, int E) {
  int e = blockIdx.x * 256 + threadIdx.x;
  if (e < E) atomicAdd(&count[H[e]], 1);
}

__global__ __launch_bounds__(256) void scan_kernel(int* count, int* row_off, int* cursor,
                                                   int N, int E) {
  __shared__ int offs[256];
  __shared__ int sums[256];
  int t = threadIdx.x;
  int chunk = (N + 255) / 256;
  int lo = t * chunk, hi = min(lo + chunk, N);
  int s = 0;
  for (int n = lo; n < hi; ++n) s += count[n];
  sums[t] = s;
  __syncthreads();
  if (t == 0) {
    int run = 0;
    for (int i = 0; i < 256; ++i) { offs[i] = run; run += sums[i]; }
  }
  __syncthreads();
  int run = offs[t];
  for (int n = lo; n < hi; ++n) {
    int c = count[n];   // count and cursor may alias: read first
    row_off[n] = run;
    cursor[n] = run;
    run += c;
  }
  if (t == 0) row_off[N] = E;
}

__global__ void scatter_kernel(const int* __restrict__ H, const int* __restrict__ S,
                               const int* __restrict__ R, int* cursor,
                               int* __restrict__ Ss, int* __restrict__ Rs,
                               int* __restrict__ inv_perm, int E) {
  int e = blockIdx.x * 256 + threadIdx.x;
  if (e < E) {
    int h = H[e];
    int pos = atomicAdd(&cursor[h], 1);
    Ss[pos] = S[e];
    Rs[pos] = R[e];
    inv_perm[e] = pos;
  }
}

// ---------------- bias_sb[inv_perm[e]][h] = bf16( sum_j Om_e[h][j] * Ra[j][e] ) -------
__global__ __launch_bounds__(256) void bias_build_kernel(const float* __restrict__ Ra,
                                                         const float* __restrict__ Om_e,
                                                         const int* __restrict__ inv_perm,
                                                         u16* __restrict__ bias_sb, int E) {
  __shared__ float OmT[64][36];  // [h][j]
  __shared__ float RaT[64][36];  // [e][j]
  int t = threadIdx.x;
  int e_base = blockIdx.x * 64;
#pragma unroll
  for (int j = 0; j < 8; ++j) {
    int f = t + 256 * j;  // 2048 = 64h x 32j
    int r = f >> 5, c = f & 31;
    OmT[r][c] = Om_e[f];
  }
#pragma unroll
  for (int j = 0; j < 8; ++j) {
    int f = t + 256 * j;  // 2048 = 32j x 64e
    int r = f >> 6, c = f & 63;
    int ee = e_base + c;
    RaT[c][r] = (ee < E) ? Ra[(size_t)r * E + ee] : 0.f;
  }
  __syncthreads();
  int ei = t & 15, h4 = (t >> 4) * 4;
  float acc[4][4] = {};
#pragma unroll 4
  for (int jj = 0; jj < 32; jj += 4) {
    float4 ra[4], om[4];
#pragma unroll
    for (int i = 0; i < 4; ++i) ra[i] = *(const float4*)&RaT[ei + 16 * i][jj];
#pragma unroll
    for (int j = 0; j < 4; ++j) om[j] = *(const float4*)&OmT[h4 + j][jj];
#pragma unroll
    for (int i = 0; i < 4; ++i)
#pragma unroll
      for (int j = 0; j < 4; ++j)
        acc[i][j] += ra[i].x * om[j].x + ra[i].y * om[j].y + ra[i].z * om[j].z +
                     ra[i].w * om[j].w;
  }
#pragma unroll
  for (int i = 0; i < 4; ++i) {
    int e = e_base + ei + 16 * i;
    if (e < E) {
      int p = inv_perm[e];
      uint2 o;
      o.x = pack2(acc[i][0], acc[i][1]);
      o.y = pack2(acc[i][2], acc[i][3]);
      *(uint2*)&bias_sb[((size_t)p << 6) + h4] = o;
    }
  }
}

// ---------------- fused iteration kernel (TN=32, weights in LDS, bf16 gathers) ------
// FIRST: X==0 => skip X staging and Wn_hat@X term.
// LAST: also run the dense head (V0/V1); skip the Xout write.
template <int FIRST, int LAST>
__global__ __launch_bounds__(256) void iter_kernel(
    const float* __restrict__ X, const u16* __restrict__ MSb_in,
    const u16* __restrict__ MRb_in, const u16* __restrict__ bias_sb,
    const int* __restrict__ Ss, const int* __restrict__ Rs,
    const int* __restrict__ row_off, const float* __restrict__ bias_n,
    const float* __restrict__ Wn_hat, const float* __restrict__ Bm,
    const float* __restrict__ W_es, const float* __restrict__ W_er,
    const float* __restrict__ V0_w, const float* __restrict__ V0_b,
    const float* __restrict__ V1_w, const float* __restrict__ V1_b,
    float* __restrict__ Xout, u16* __restrict__ MSb_out,
    u16* __restrict__ MRb_out, float* __restrict__ head_out, int N) {
  __shared__ float Wa[64][ST], Wb[64][ST];
  __shared__ float Xsh[TN][ST], Ash[TN][ST];
  __shared__ float b0s[64], b1s[64];
  int t = threadIdx.x;
  int n_base = blockIdx.x * TN;
  // stage phase-A weights
#pragma unroll
  for (int j = 0; j < 16; ++j) {
    int f = t + 256 * j;
    int r = f >> 6, c = f & 63;
    Wa[r][c] = Wn_hat[f];
    Wb[r][c] = Bm[f];
  }
  int n8 = t >> 3;   // node slot 0..31
  int q8 = t & 7;    // 8-h chunk 0..7
  int nd = n_base + n8;
  bool ok = nd < N;
  if (!FIRST) {
    float4 x0 = make_float4(0, 0, 0, 0), x1 = x0;
    if (ok) {
      x0 = *(const float4*)&X[(size_t)nd * 64 + q8 * 8];
      x1 = *(const float4*)&X[(size_t)nd * 64 + q8 * 8 + 4];
    }
    *(float4*)&Xsh[n8][q8 * 8] = x0;
    *(float4*)&Xsh[n8][q8 * 8 + 4] = x1;
  }
  // agg phase: 8 threads/node, each handles 8 h-values (bf16 rows = one uint4/stream)
  float a[8] = {};
  if (ok) {
    int r0 = row_off[nd], r1 = row_off[nd + 1];
    for (int p = r0; p < r1; ++p) {
      uint4 bv = *(const uint4*)&bias_sb[((size_t)p << 6) + q8 * 8];
      if (FIRST) {
        a[0] += relu_f(bf_lo(bv.x)); a[1] += relu_f(bf_hi(bv.x));
        a[2] += relu_f(bf_lo(bv.y)); a[3] += relu_f(bf_hi(bv.y));
        a[4] += relu_f(bf_lo(bv.z)); a[5] += relu_f(bf_hi(bv.z));
        a[6] += relu_f(bf_lo(bv.w)); a[7] += relu_f(bf_hi(bv.w));
      } else {
        int s = Ss[p], r = Rs[p];
        uint4 mv = *(const uint4*)&MSb_in[((size_t)s << 6) + q8 * 8];
        uint4 rv = *(const uint4*)&MRb_in[((size_t)r << 6) + q8 * 8];
        a[0] += relu_f(bf_lo(mv.x) + bf_lo(rv.x) + bf_lo(bv.x));
        a[1] += relu_f(bf_hi(mv.x) + bf_hi(rv.x) + bf_hi(bv.x));
        a[2] += relu_f(bf_lo(mv.y) + bf_lo(rv.y) + bf_lo(bv.y));
        a[3] += relu_f(bf_hi(mv.y) + bf_hi(rv.y) + bf_hi(bv.y));
        a[4] += relu_f(bf_lo(mv.z) + bf_lo(rv.z) + bf_lo(bv.z));
        a[5] += relu_f(bf_hi(mv.z) + bf_hi(rv.z) + bf_hi(bv.z));
        a[6] += relu_f(bf_lo(mv.w) + bf_lo(rv.w) + bf_lo(bv.w));
        a[7] += relu_f(bf_hi(mv.w) + bf_hi(rv.w) + bf_hi(bv.w));
      }
    }
  }
  *(float4*)&Ash[n8][q8 * 8] = make_float4(a[0], a[1], a[2], a[3]);
  *(float4*)&Ash[n8][q8 * 8 + 4] = make_float4(a[4], a[5], a[6], a[7]);
  __syncthreads();
  // phase A (fused): acc = Wn_hat@X + Bm@agg ; rows = ni, ni+16; cols = h4..h4+3
  int ni = t & 15, h4 = (t >> 4) * 4;
  float acc[2][4] = {};
#pragma unroll 4
  for (int k = 0; k < 64; k += 4) {
    float4 xv[2], av[2], wv[4], bv[4];
#pragma unroll
    for (int i = 0; i < 2; ++i) {
      if (!FIRST) xv[i] = *(const float4*)&Xsh[ni + 16 * i][k];
      av[i] = *(const float4*)&Ash[ni + 16 * i][k];
    }
#pragma unroll
    for (int j = 0; j < 4; ++j) {
      wv[j] = *(const float4*)&Wa[h4 + j][k];
      bv[j] = *(const float4*)&Wb[h4 + j][k];
    }
#pragma unroll
    for (int i = 0; i < 2; ++i)
#pragma unroll
      for (int j = 0; j < 4; ++j) {
        float v = av[i].x * bv[j].x + av[i].y * bv[j].y + av[i].z * bv[j].z +
                  av[i].w * bv[j].w;
        if (!FIRST)
          v += xv[i].x * wv[j].x + xv[i].y * wv[j].y + xv[i].z * wv[j].z +
               xv[i].w * wv[j].w;
        acc[i][j] += v;
      }
  }
  __syncthreads();  // phase-A reads of Xsh/Ash/Wa/Wb done
  // epilogue A: xnew = relu(acc + bias_n) -> Xsh (and Xout unless LAST)
#pragma unroll
  for (int i = 0; i < 2; ++i) {
    int nn = n_base + ni + 16 * i;
    float4 bb = make_float4(0, 0, 0, 0);
    if (nn < N) bb = *(const float4*)&bias_n[(size_t)nn * 64 + h4];
    float x0 = relu_f(acc[i][0] + bb.x);
    float x1 = relu_f(acc[i][1] + bb.y);
    float x2 = relu_f(acc[i][2] + bb.z);
    float x3 = relu_f(acc[i][3] + bb.w);
    if (!LAST && nn < N)
      *(float4*)&Xout[(size_t)nn * 64 + h4] = make_float4(x0, x1, x2, x3);
    *(float4*)&Xsh[ni + 16 * i][h4] = make_float4(x0, x1, x2, x3);
  }
  // stage phase-B weights (Wa/Wb reads all done at last barrier)
#pragma unroll
  for (int j = 0; j < 16; ++j) {
    int f = t + 256 * j;
    int r = f >> 6, c = f & 63;
    Wa[r][c] = W_es[f];
    Wb[r][c] = W_er[f];
  }
  __syncthreads();
  // phase B: MS = bf16(Wes@xnew), MR = bf16(Wer@xnew)
  {
    float ma[2][4] = {}, ra[2][4] = {};
#pragma unroll 4
    for (int k = 0; k < 64; k += 4) {
      float4 xv[2], ws[4], wr[4];
#pragma unroll
      for (int i = 0; i < 2; ++i) xv[i] = *(const float4*)&Xsh[ni + 16 * i][k];
#pragma unroll
      for (int j = 0; j < 4; ++j) {
        ws[j] = *(const float4*)&Wa[h4 + j][k];
        wr[j] = *(const float4*)&Wb[h4 + j][k];
      }
#pragma unroll
      for (int i = 0; i < 2; ++i)
#pragma unroll
        for (int j = 0; j < 4; ++j) {
          ma[i][j] += xv[i].x * ws[j].x + xv[i].y * ws[j].y + xv[i].z * ws[j].z +
                      xv[i].w * ws[j].w;
          ra[i][j] += xv[i].x * wr[j].x + xv[i].y * wr[j].y + xv[i].z * wr[j].z +
                      xv[i].w * wr[j].w;
        }
    }
#pragma unroll
    for (int i = 0; i < 2; ++i) {
      int nn = n_base + ni + 16 * i;
      if (nn < N) {
        uint2 om, orr;
        om.x = pack2(ma[i][0], ma[i][1]);
        om.y = pack2(ma[i][2], ma[i][3]);
        orr.x = pack2(ra[i][0], ra[i][1]);
        orr.y = pack2(ra[i][2], ra[i][3]);
        *(uint2*)&MSb_out[((size_t)nn << 6) + h4] = om;
        *(uint2*)&MRb_out[((size_t)nn << 6) + h4] = orr;
      }
    }
  }
  if (LAST) {
    __syncthreads();  // phase-B reads of Wa/Wb done
#pragma unroll
    for (int j = 0; j < 16; ++j) {
      int f = t + 256 * j;
      int r = f >> 6, c = f & 63;
      Wa[r][c] = V0_w[f];
      Wb[r][c] = V1_w[f];
    }
    if (t < 64) b0s[t] = V0_b[t];
    else if (t < 128) b1s[t - 64] = V1_b[t - 64];
    __syncthreads();
    // phase C: c1 = xnew @ V0^T (registers)
    float c1[2][4] = {};
#pragma unroll 4
    for (int k = 0; k < 64; k += 4) {
      float4 xv[2], wv[4];
#pragma unroll
      for (int i = 0; i < 2; ++i) xv[i] = *(const float4*)&Xsh[ni + 16 * i][k];
#pragma unroll
      for (int j = 0; j < 4; ++j) wv[j] = *(const float4*)&Wa[h4 + j][k];
#pragma unroll
      for (int i = 0; i < 2; ++i)
#pragma unroll
        for (int j = 0; j < 4; ++j)
          c1[i][j] += xv[i].x * wv[j].x + xv[i].y * wv[j].y + xv[i].z * wv[j].z +
                      xv[i].w * wv[j].w;
    }
    __syncthreads();  // phase-C reads of Xsh done
    // x1 = relu(c1 + b0) -> Xsh
#pragma unroll
    for (int i = 0; i < 2; ++i) {
      float4 o;
      o.x = relu_f(c1[i][0] + b0s[h4 + 0]);
      o.y = relu_f(c1[i][1] + b0s[h4 + 1]);
      o.z = relu_f(c1[i][2] + b0s[h4 + 2]);
      o.w = relu_f(c1[i][3] + b0s[h4 + 3]);
      *(float4*)&Xsh[ni + 16 * i][h4] = o;
    }
    __syncthreads();
    // phase D: out = x1 @ V1^T + b1
    float c2[2][4] = {};
#pragma unroll 4
    for (int k = 0; k < 64; k += 4) {
      float4 xv[2], wv[4];
#pragma unroll
      for (int i = 0; i < 2; ++i) xv[i] = *(const float4*)&Xsh[ni + 16 * i][k];
#pragma unroll
      for (int j = 0; j < 4; ++j) wv[j] = *(const float4*)&Wb[h4 + j][k];
#pragma unroll
      for (int i = 0; i < 2; ++i)
#pragma unroll
        for (int j = 0; j < 4; ++j)
          c2[i][j] += xv[i].x * wv[j].x + xv[i].y * wv[j].y + xv[i].z * wv[j].z +
                      xv[i].w * wv[j].w;
    }
#pragma unroll
    for (int i = 0; i < 2; ++i) {
      int nn = n_base + ni + 16 * i;
      if (nn < N) {
        float4 o;
        o.x = c2[i][0] + b1s[h4 + 0];
        o.y = c2[i][1] + b1s[h4 + 1];
        o.z = c2[i][2] + b1s[h4 + 2];
        o.w = c2[i][3] + b1s[h4 + 3];
        *(float4*)&head_out[(size_t)nn * 64 + h4] = o;
      }
    }
  }
}

// ---------------- final edge kernel: bf16 gather + Om@Ra bias + transpose ----------
// He_logits[h][e] = MS[S[e]][h] + MR[R[e]][h] + (Om_e@Ra)[h][e]
__global__ __launch_bounds__(256) void edge_final_kernel(
    const u16* __restrict__ MSb, const u16* __restrict__ MRb,
    const int* __restrict__ S, const int* __restrict__ R,
    const float* __restrict__ Om_e, const float* __restrict__ Ra,
    float* __restrict__ He_out, float* __restrict__ Hel_out, int E) {
  __shared__ float T[64][ST];     // [e][h] gather tile
  __shared__ float pool2[4608];   // OmT[64][36] + RaT[64][36]; later transpose (64*65)
  int t = threadIdx.x;
  int e_base = blockIdx.x * 64;
#pragma unroll
  for (int j = 0; j < 8; ++j) {
    int f = t + 256 * j;  // 2048 = 64h x 32j
    int r = f >> 5, c = f & 31;
    pool2[r * 36 + c] = Om_e[f];
  }
#pragma unroll
  for (int j = 0; j < 8; ++j) {
    int f = t + 256 * j;  // 2048 = 32j x 64e
    int r = f >> 6, c = f & 63;
    int e2 = e_base + c;
    pool2[2304 + c * 36 + r] = (e2 < E) ? Ra[(size_t)r * E + e2] : 0.f;
  }
  // gather MS[S]+MR[R] into T (bf16 rows: 16 h = 2 uint4 per thread per stream)
  {
    int e = t >> 2, q = t & 3;
    int ee = e_base + e;
    int ec = (ee < E) ? ee : 0;
    int s = S[ec], r = R[ec];
    const u16* mp = &MSb[((size_t)s << 6) + q * 16];
    const u16* rp = &MRb[((size_t)r << 6) + q * 16];
    uint4 m0 = *(const uint4*)mp;
    uint4 m1 = *(const uint4*)(mp + 8);
    uint4 r0 = *(const uint4*)rp;
    uint4 r1 = *(const uint4*)(rp + 8);
    float* tp = &T[e][q * 16];
    tp[0] = bf_lo(m0.x) + bf_lo(r0.x);
    tp[1] = bf_hi(m0.x) + bf_hi(r0.x);
    tp[2] = bf_lo(m0.y) + bf_lo(r0.y);
    tp[3] = bf_hi(m0.y) + bf_hi(r0.y);
    tp[4] = bf_lo(m0.z) + bf_lo(r0.z);
    tp[5] = bf_hi(m0.z) + bf_hi(r0.z);
    tp[6] = bf_lo(m0.w) + bf_lo(r0.w);
    tp[7] = bf_hi(m0.w) + bf_hi(r0.w);
    tp[8] = bf_lo(m1.x) + bf_lo(r1.x);
    tp[9] = bf_hi(m1.x) + bf_hi(r1.x);
    tp[10] = bf_lo(m1.y) + bf_lo(r1.y);
    tp[11] = bf_hi(m1.y) + bf_hi(r1.y);
    tp[12] = bf_lo(m1.z) + bf_lo(r1.z);
    tp[13] = bf_hi(m1.z) + bf_hi(r1.z);
    tp[14] = bf_lo(m1.w) + bf_lo(r1.w);
    tp[15] = bf_hi(m1.w) + bf_hi(r1.w);
  }
  __syncthreads();
  int ei = t & 15, h4 = (t >> 4) * 4;
  float acc[4][4] = {};
#pragma unroll 4
  for (int jj = 0; jj < 32; jj += 4) {
    float4 ra[4], om[4];
#pragma unroll
    for (int i = 0; i < 4; ++i)
      ra[i] = *(const float4*)&pool2[2304 + (ei + 16 * i) * 36 + jj];
#pragma unroll
    for (int j = 0; j < 4; ++j) om[j] = *(const float4*)&pool2[(h4 + j) * 36 + jj];
#pragma unroll
    for (int i = 0; i < 4; ++i)
#pragma unroll
      for (int j = 0; j < 4; ++j)
        acc[i][j] += ra[i].x * om[j].x + ra[i].y * om[j].y + ra[i].z * om[j].z +
                     ra[i].w * om[j].w;
  }
  // add gathered MS+MR
#pragma unroll
  for (int i = 0; i < 4; ++i) {
    float4 tv = *(const float4*)&T[ei + 16 * i][h4];
    acc[i][0] += tv.x;
    acc[i][1] += tv.y;
    acc[i][2] += tv.z;
    acc[i][3] += tv.w;
  }
  __syncthreads();  // done reading pool2 (OmT/RaT) and T
  // transpose via pool2 (stride 65 -> conflict-light column reads)
#pragma unroll
  for (int i = 0; i < 4; ++i)
#pragma unroll
    for (int j = 0; j < 4; ++j)
      pool2[(ei + 16 * i) * 65 + h4 + j] = acc[i][j];
  __syncthreads();
  {
    int e4 = (t & 15) * 4, h0 = t >> 4;
#pragma unroll
    for (int rep = 0; rep < 4; ++rep) {
      int h = h0 + 16 * rep;
      float4 v;
      v.x = pool2[(e4 + 0) * 65 + h];
      v.y = pool2[(e4 + 1) * 65 + h];
      v.z = pool2[(e4 + 2) * 65 + h];
      v.w = pool2[(e4 + 3) * 65 + h];
      size_t idx = (size_t)h * E + e_base + e4;
      if (e_base + e4 < E) {
        *(float4*)&Hel_out[idx] = v;
        float4 u = make_float4(relu_f(v.x), relu_f(v.y), relu_f(v.z), relu_f(v.w));
        *(float4*)&He_out[idx] = u;
      }
    }
  }
}

extern "C" void kernel_launch(void* const* d_in, const int* in_sizes, int n_in,
                              void* d_out, int out_size, void* d_ws, size_t ws_size,
                              hipStream_t stream) {
  const int* R = (const int*)d_in[0];
  const int* S = (const int*)d_in[1];
  const int* H = (const int*)d_in[2];
  const float* node_data = (const float*)d_in[3];
  const float* Ra = (const float*)d_in[4];
  const float* W_es = (const float*)d_in[5];
  const float* W_er = (const float*)d_in[6];
  const float* Om_e = (const float*)d_in[7];
  const float* Wn = (const float*)d_in[8];
  const float* Bm = (const float*)d_in[9];
  const float* Om_n = (const float*)d_in[10];
  const float* V0_w = (const float*)d_in[11];
  const float* V0_b = (const float*)d_in[12];
  const float* V1_w = (const float*)d_in[13];
  const float* V1_b = (const float*)d_in[14];
  const int E = in_sizes[0];
  const int N = in_sizes[3] / 64;
  const size_t N64 = (size_t)N * 64;

  float* ws = (float*)d_ws;
  float* Wn_hat = ws;                    // 4096 floats
  float* bias_n = Wn_hat + 4096;         // N64 floats
  float* X0 = bias_n + N64;              // N64 floats
  float* X1p = X0 + N64;                 // N64 floats
  u16* MSb_B = (u16*)(X1p + N64);        // N64 u16 (odd-iter MS; final MS)
  u16* MRb_B = MSb_B + N64;              // N64 u16
  int* row_off = (int*)(MRb_B + N64);    // N+1
  int* cursor = row_off + (N + 1);       // N (doubles as histogram)
  int* Ss = cursor + N;                  // E
  int* Rs = Ss + E;                      // E
  int* inv_perm = Rs + E;                // E

  float* out = (float*)d_out;
  float* out_x = out;                          // [N][64]
  float* out_He = out + N64;                   // [64][E]
  float* out_Hel = out_He + (size_t)64 * E;    // [64][E]
  u16* bias_sb = (u16*)out_He;   // He region: bf16 sorted-bias scratch during iters
  u16* MSb_A = (u16*)out_Hel;    // Hel region: even-iter MS/MR (dead before final)
  u16* MRb_A = MSb_A + N64;

  int nb_node = (N + 63) / 64;
  int nb_iter = (N + TN - 1) / TN;
  int nb_edge = (E + 63) / 64;
  int nb_flat = (E + 255) / 256;

  hipMemsetAsync(cursor, 0, (size_t)N * sizeof(int), stream);
  wnhat_kernel<<<1, 256, 0, stream>>>(Wn, Wn_hat);
  bias_n_kernel<<<nb_node, 256, 0, stream>>>(node_data, Om_n, bias_n, N);
  hist_kernel<<<nb_flat, 256, 0, stream>>>(H, cursor, E);
  scan_kernel<<<1, 256, 0, stream>>>(cursor, row_off, cursor, N, E);
  scatter_kernel<<<nb_flat, 256, 0, stream>>>(H, S, R, cursor, Ss, Rs, inv_perm, E);
  bias_build_kernel<<<nb_edge, 256, 0, stream>>>(Ra, Om_e, inv_perm, bias_sb, E);

  float* Xa = X0;
  float* Xb = X1p;
  const u16* msi = nullptr;
  const u16* mri = nullptr;
  for (int it = 0; it < 8; ++it) {
    u16* mso = (it & 1) ? MSb_B : MSb_A;
    u16* mro = (it & 1) ? MRb_B : MRb_A;
    if (it == 0)
      iter_kernel<1, 0><<<nb_iter, 256, 0, stream>>>(
          Xa, nullptr, nullptr, bias_sb, Ss, Rs, row_off, bias_n, Wn_hat, Bm, W_es, W_er,
          V0_w, V0_b, V1_w, V1_b, Xb, mso, mro, out_x, N);
    else if (it < 7)
      iter_kernel<0, 0><<<nb_iter, 256, 0, stream>>>(
          Xa, msi, mri, bias_sb, Ss, Rs, row_off, bias_n, Wn_hat, Bm, W_es, W_er,
          V0_w, V0_b, V1_w, V1_b, Xb, mso, mro, out_x, N);
    else
      iter_kernel<0, 1><<<nb_iter, 256, 0, stream>>>(
          Xa, msi, mri, bias_sb, Ss, Rs, row_off, bias_n, Wn_hat, Bm, W_es, W_er,
          V0_w, V0_b, V1_w, V1_b, Xb, mso, mro, out_x, N);
    msi = mso;
    mri = mro;
    float* tmp = Xa; Xa = Xb; Xb = tmp;
  }
  // it=7 (odd) wrote MSb_B/MRb_B in ws; He/Hel regions are free to write now.
  edge_final_kernel<<<nb_edge, 256, 0, stream>>>(MSb_B, MRb_B, S, R, Om_e, Ra,
                                                 out_He, out_Hel, E);
}

// Round 13
// 436.171 us; speedup vs baseline: 1.4025x; 1.1148x over previous
//
#include <hip/hip_runtime.h>
#include <math.h>

#define KAPPA 0.9f
#define ST 68   // LDS row stride (64+4); 68%32=4 -> 2-way aliasing (free)
#define TN 32   // nodes per iter-kernel tile (625 blocks)

typedef unsigned short u16;

__device__ __forceinline__ float relu_f(float v) { return fmaxf(v, 0.0f); }
__device__ __forceinline__ float bf_lo(unsigned u) { return __uint_as_float(u << 16); }
__device__ __forceinline__ float bf_hi(unsigned u) { return __uint_as_float(u & 0xFFFF0000u); }
__device__ __forceinline__ u16 f2bf(float x) {
  unsigned u = __float_as_uint(x);
  return (u16)((u + 0x7FFFu + ((u >> 16) & 1u)) >> 16);
}
__device__ __forceinline__ unsigned pack2(float a, float b) {
  return (unsigned)f2bf(a) | ((unsigned)f2bf(b) << 16);
}

// ---------------- Wn_hat = KAPPA * Wn / max(||Wn||_F, 1) ----------------
__global__ __launch_bounds__(256) void wnhat_kernel(const float* __restrict__ Wn,
                                                    float* __restrict__ Wn_hat) {
  __shared__ float red[4];
  int t = threadIdx.x;
  float v[16];
  float s = 0.f;
#pragma unroll
  for (int j = 0; j < 16; ++j) { v[j] = Wn[t + 256 * j]; s += v[j] * v[j]; }
#pragma unroll
  for (int off = 32; off > 0; off >>= 1) s += __shfl_down(s, off, 64);
  if ((t & 63) == 0) red[t >> 6] = s;
  __syncthreads();
  float norm = sqrtf(red[0] + red[1] + red[2] + red[3]);
  float scale = KAPPA / fmaxf(norm, 1.0f);
#pragma unroll
  for (int j = 0; j < 16; ++j) Wn_hat[t + 256 * j] = v[j] * scale;
}

// ---------------- bias_n[n][h] = sum_k Om_n[h][k] * node_data[k][n] ----------------
__global__ __launch_bounds__(256) void bias_n_kernel(const float* __restrict__ node_data,
                                                     const float* __restrict__ Om_n,
                                                     float* __restrict__ bias_n, int N) {
  __shared__ float NdT[64][ST];  // [n][k]
  __shared__ float Om[64][ST];   // [h][k]
  int t = threadIdx.x;
  int n_base = blockIdx.x * 64;
#pragma unroll
  for (int j = 0; j < 16; ++j) {
    int f = t + 256 * j;
    int r = f >> 6, c = f & 63;
    float val = (n_base + c < N) ? node_data[(size_t)r * N + n_base + c] : 0.f;
    NdT[c][r] = val;
    Om[r][c] = Om_n[f];
  }
  __syncthreads();
  int ni = t & 15, h4 = (t >> 4) * 4;
  float acc[4][4] = {};
#pragma unroll 4
  for (int k = 0; k < 64; k += 4) {
    float4 a[4], w[4];
#pragma unroll
    for (int i = 0; i < 4; ++i) a[i] = *(const float4*)&NdT[ni + 16 * i][k];
#pragma unroll
    for (int j = 0; j < 4; ++j) w[j] = *(const float4*)&Om[h4 + j][k];
#pragma unroll
    for (int i = 0; i < 4; ++i)
#pragma unroll
      for (int j = 0; j < 4; ++j)
        acc[i][j] += a[i].x * w[j].x + a[i].y * w[j].y + a[i].z * w[j].z + a[i].w * w[j].w;
  }
#pragma unroll
  for (int i = 0; i < 4; ++i) {
    int n = n_base + ni + 16 * i;
    if (n < N) {
      float4 o = make_float4(acc[i][0], acc[i][1], acc[i][2], acc[i][3]);
      *(float4*)&bias_n[(size_t)n * 64 + h4] = o;
    }
  }
}

// ---------------- CSR build: histogram / scan / scatter ----------------
__global__ void hist_kernel(const int* __restrict__ H, int* __restrict__ count, int E) {
  int e = blockIdx.x * 256 + threadIdx.x;
  if (e < E) atomicAdd(&count[H[e]], 1);
}

__global__ __launch_bounds__(256) void scan_kernel(int* count, int* row_off, int* cursor,
                                                   int N, int E) {
  __shared__ int offs[256];
  __shared__ int sums[256];
  int t = threadIdx.x;
  int chunk = (N + 255) / 256;
  int lo = t * chunk, hi = min(lo + chunk, N);
  int s = 0;
  for (int n = lo; n < hi; ++n) s += count[n];
  sums[t] = s;
  __syncthreads();
  if (t == 0) {
    int run = 0;
    for (int i = 0; i < 256; ++i) { offs[i] = run; run += sums[i]; }
  }
  __syncthreads();
  int run = offs[t];
  for (int n = lo; n < hi; ++n) {
    int c = count[n];   // count and cursor may alias: read first
    row_off[n] = run;
    cursor[n] = run;
    run += c;
  }
  if (t == 0) row_off[N] = E;
}

__global__ void scatter_kernel(const int* __restrict__ H, const int* __restrict__ S,
                               const int* __restrict__ R, int* cursor,
                               int2* __restrict__ SRs, int* __restrict__ inv_perm, int E) {
  int e = blockIdx.x * 256 + threadIdx.x;
  if (e < E) {
    int h = H[e];
    int pos = atomicAdd(&cursor[h], 1);
    SRs[pos] = make_int2(S[e], R[e]);
    inv_perm[e] = pos;
  }
}

// ---------------- bias_sb[inv_perm[e]][h] = bf16( sum_j Om_e[h][j] * Ra[j][e] ) -------
__global__ __launch_bounds__(256) void bias_build_kernel(const float* __restrict__ Ra,
                                                         const float* __restrict__ Om_e,
                                                         const int* __restrict__ inv_perm,
                                                         u16* __restrict__ bias_sb, int E) {
  __shared__ float OmT[64][36];  // [h][j]
  __shared__ float RaT[64][36];  // [e][j]
  int t = threadIdx.x;
  int e_base = blockIdx.x * 64;
#pragma unroll
  for (int j = 0; j < 8; ++j) {
    int f = t + 256 * j;  // 2048 = 64h x 32j
    int r = f >> 5, c = f & 31;
    OmT[r][c] = Om_e[f];
  }
#pragma unroll
  for (int j = 0; j < 8; ++j) {
    int f = t + 256 * j;  // 2048 = 32j x 64e
    int r = f >> 6, c = f & 63;
    int ee = e_base + c;
    RaT[c][r] = (ee < E) ? Ra[(size_t)r * E + ee] : 0.f;
  }
  __syncthreads();
  int ei = t & 15, h4 = (t >> 4) * 4;
  float acc[4][4] = {};
#pragma unroll 4
  for (int jj = 0; jj < 32; jj += 4) {
    float4 ra[4], om[4];
#pragma unroll
    for (int i = 0; i < 4; ++i) ra[i] = *(const float4*)&RaT[ei + 16 * i][jj];
#pragma unroll
    for (int j = 0; j < 4; ++j) om[j] = *(const float4*)&OmT[h4 + j][jj];
#pragma unroll
    for (int i = 0; i < 4; ++i)
#pragma unroll
      for (int j = 0; j < 4; ++j)
        acc[i][j] += ra[i].x * om[j].x + ra[i].y * om[j].y + ra[i].z * om[j].z +
                     ra[i].w * om[j].w;
  }
#pragma unroll
  for (int i = 0; i < 4; ++i) {
    int e = e_base + ei + 16 * i;
    if (e < E) {
      int p = inv_perm[e];
      uint2 o;
      o.x = pack2(acc[i][0], acc[i][1]);
      o.y = pack2(acc[i][2], acc[i][3]);
      *(uint2*)&bias_sb[((size_t)p << 6) + h4] = o;
    }
  }
}

// ---------------- fused iteration kernel (TN=32, 4-wide pipelined gathers) ----------
// FIRST: X==0 => skip X staging and Wn_hat@X term.
// LAST: also run the dense head (V0/V1); skip the Xout write.
template <int FIRST, int LAST>
__global__ __launch_bounds__(256) void iter_kernel(
    const float* __restrict__ X, const u16* __restrict__ MSb_in,
    const u16* __restrict__ MRb_in, const u16* __restrict__ bias_sb,
    const int2* __restrict__ SRs, const int* __restrict__ row_off,
    const float* __restrict__ bias_n, const float* __restrict__ Wn_hat,
    const float* __restrict__ Bm, const float* __restrict__ W_es,
    const float* __restrict__ W_er, const float* __restrict__ V0_w,
    const float* __restrict__ V0_b, const float* __restrict__ V1_w,
    const float* __restrict__ V1_b, float* __restrict__ Xout,
    u16* __restrict__ MSb_out, u16* __restrict__ MRb_out,
    float* __restrict__ head_out, int N) {
  __shared__ float Wa[64][ST], Wb[64][ST];
  __shared__ float Xsh[TN][ST], Ash[TN][ST];
  __shared__ float b0s[64], b1s[64];
  int t = threadIdx.x;
  int n_base = blockIdx.x * TN;
  // stage phase-A weights
#pragma unroll
  for (int j = 0; j < 16; ++j) {
    int f = t + 256 * j;
    int r = f >> 6, c = f & 63;
    Wa[r][c] = Wn_hat[f];
    Wb[r][c] = Bm[f];
  }
  int n8 = t >> 3;   // node slot 0..31
  int q8 = t & 7;    // 8-h chunk 0..7
  int nd = n_base + n8;
  bool ok = nd < N;
  if (!FIRST) {
    float4 x0 = make_float4(0, 0, 0, 0), x1 = x0;
    if (ok) {
      x0 = *(const float4*)&X[(size_t)nd * 64 + q8 * 8];
      x1 = *(const float4*)&X[(size_t)nd * 64 + q8 * 8 + 4];
    }
    *(float4*)&Xsh[n8][q8 * 8] = x0;
    *(float4*)&Xsh[n8][q8 * 8 + 4] = x1;
  }
  // agg phase: 8 threads/node, 4-wide software-pipelined edge loop
  float a[8] = {};
  if (ok) {
    int r0 = row_off[nd], r1 = row_off[nd + 1];
    for (int p = r0; p < r1; p += 4) {
      uint4 bv[4], mv[4], rv[4];
      if (FIRST) {
#pragma unroll
        for (int u = 0; u < 4; ++u) {
          int pc = min(p + u, r1 - 1);
          bv[u] = *(const uint4*)&bias_sb[((size_t)pc << 6) + q8 * 8];
        }
      } else {
        int2 sr[4];
#pragma unroll
        for (int u = 0; u < 4; ++u) {
          int pc = min(p + u, r1 - 1);
          sr[u] = SRs[pc];
          bv[u] = *(const uint4*)&bias_sb[((size_t)pc << 6) + q8 * 8];
        }
#pragma unroll
        for (int u = 0; u < 4; ++u) {
          mv[u] = *(const uint4*)&MSb_in[((size_t)sr[u].x << 6) + q8 * 8];
          rv[u] = *(const uint4*)&MRb_in[((size_t)sr[u].y << 6) + q8 * 8];
        }
      }
#pragma unroll
      for (int u = 0; u < 4; ++u) {
        if (p + u < r1) {
          if (FIRST) {
            a[0] += relu_f(bf_lo(bv[u].x)); a[1] += relu_f(bf_hi(bv[u].x));
            a[2] += relu_f(bf_lo(bv[u].y)); a[3] += relu_f(bf_hi(bv[u].y));
            a[4] += relu_f(bf_lo(bv[u].z)); a[5] += relu_f(bf_hi(bv[u].z));
            a[6] += relu_f(bf_lo(bv[u].w)); a[7] += relu_f(bf_hi(bv[u].w));
          } else {
            a[0] += relu_f(bf_lo(mv[u].x) + bf_lo(rv[u].x) + bf_lo(bv[u].x));
            a[1] += relu_f(bf_hi(mv[u].x) + bf_hi(rv[u].x) + bf_hi(bv[u].x));
            a[2] += relu_f(bf_lo(mv[u].y) + bf_lo(rv[u].y) + bf_lo(bv[u].y));
            a[3] += relu_f(bf_hi(mv[u].y) + bf_hi(rv[u].y) + bf_hi(bv[u].y));
            a[4] += relu_f(bf_lo(mv[u].z) + bf_lo(rv[u].z) + bf_lo(bv[u].z));
            a[5] += relu_f(bf_hi(mv[u].z) + bf_hi(rv[u].z) + bf_hi(bv[u].z));
            a[6] += relu_f(bf_lo(mv[u].w) + bf_lo(rv[u].w) + bf_lo(bv[u].w));
            a[7] += relu_f(bf_hi(mv[u].w) + bf_hi(rv[u].w) + bf_hi(bv[u].w));
          }
        }
      }
    }
  }
  *(float4*)&Ash[n8][q8 * 8] = make_float4(a[0], a[1], a[2], a[3]);
  *(float4*)&Ash[n8][q8 * 8 + 4] = make_float4(a[4], a[5], a[6], a[7]);
  __syncthreads();
  // phase A (fused): acc = Wn_hat@X + Bm@agg ; rows = ni, ni+16; cols = h4..h4+3
  int ni = t & 15, h4 = (t >> 4) * 4;
  float acc[2][4] = {};
#pragma unroll 4
  for (int k = 0; k < 64; k += 4) {
    float4 xv[2], av[2], wv[4], bv[4];
#pragma unroll
    for (int i = 0; i < 2; ++i) {
      if (!FIRST) xv[i] = *(const float4*)&Xsh[ni + 16 * i][k];
      av[i] = *(const float4*)&Ash[ni + 16 * i][k];
    }
#pragma unroll
    for (int j = 0; j < 4; ++j) {
      wv[j] = *(const float4*)&Wa[h4 + j][k];
      bv[j] = *(const float4*)&Wb[h4 + j][k];
    }
#pragma unroll
    for (int i = 0; i < 2; ++i)
#pragma unroll
      for (int j = 0; j < 4; ++j) {
        float v = av[i].x * bv[j].x + av[i].y * bv[j].y + av[i].z * bv[j].z +
                  av[i].w * bv[j].w;
        if (!FIRST)
          v += xv[i].x * wv[j].x + xv[i].y * wv[j].y + xv[i].z * wv[j].z +
               xv[i].w * wv[j].w;
        acc[i][j] += v;
      }
  }
  __syncthreads();  // phase-A reads of Xsh/Ash/Wa/Wb done
  // epilogue A: xnew = relu(acc + bias_n) -> Xsh (and Xout unless LAST)
#pragma unroll
  for (int i = 0; i < 2; ++i) {
    int nn = n_base + ni + 16 * i;
    float4 bb = make_float4(0, 0, 0, 0);
    if (nn < N) bb = *(const float4*)&bias_n[(size_t)nn * 64 + h4];
    float x0 = relu_f(acc[i][0] + bb.x);
    float x1 = relu_f(acc[i][1] + bb.y);
    float x2 = relu_f(acc[i][2] + bb.z);
    float x3 = relu_f(acc[i][3] + bb.w);
    if (!LAST && nn < N)
      *(float4*)&Xout[(size_t)nn * 64 + h4] = make_float4(x0, x1, x2, x3);
    *(float4*)&Xsh[ni + 16 * i][h4] = make_float4(x0, x1, x2, x3);
  }
  // stage phase-B weights (Wa/Wb reads all done at last barrier)
#pragma unroll
  for (int j = 0; j < 16; ++j) {
    int f = t + 256 * j;
    int r = f >> 6, c = f & 63;
    Wa[r][c] = W_es[f];
    Wb[r][c] = W_er[f];
  }
  __syncthreads();
  // phase B: MS = bf16(Wes@xnew), MR = bf16(Wer@xnew)
  {
    float ma[2][4] = {}, ra[2][4] = {};
#pragma unroll 4
    for (int k = 0; k < 64; k += 4) {
      float4 xv[2], ws[4], wr[4];
#pragma unroll
      for (int i = 0; i < 2; ++i) xv[i] = *(const float4*)&Xsh[ni + 16 * i][k];
#pragma unroll
      for (int j = 0; j < 4; ++j) {
        ws[j] = *(const float4*)&Wa[h4 + j][k];
        wr[j] = *(const float4*)&Wb[h4 + j][k];
      }
#pragma unroll
      for (int i = 0; i < 2; ++i)
#pragma unroll
        for (int j = 0; j < 4; ++j) {
          ma[i][j] += xv[i].x * ws[j].x + xv[i].y * ws[j].y + xv[i].z * ws[j].z +
                      xv[i].w * ws[j].w;
          ra[i][j] += xv[i].x * wr[j].x + xv[i].y * wr[j].y + xv[i].z * wr[j].z +
                      xv[i].w * wr[j].w;
        }
    }
#pragma unroll
    for (int i = 0; i < 2; ++i) {
      int nn = n_base + ni + 16 * i;
      if (nn < N) {
        uint2 om, orr;
        om.x = pack2(ma[i][0], ma[i][1]);
        om.y = pack2(ma[i][2], ma[i][3]);
        orr.x = pack2(ra[i][0], ra[i][1]);
        orr.y = pack2(ra[i][2], ra[i][3]);
        *(uint2*)&MSb_out[((size_t)nn << 6) + h4] = om;
        *(uint2*)&MRb_out[((size_t)nn << 6) + h4] = orr;
      }
    }
  }
  if (LAST) {
    __syncthreads();  // phase-B reads of Wa/Wb done
#pragma unroll
    for (int j = 0; j < 16; ++j) {
      int f = t + 256 * j;
      int r = f >> 6, c = f & 63;
      Wa[r][c] = V0_w[f];
      Wb[r][c] = V1_w[f];
    }
    if (t < 64) b0s[t] = V0_b[t];
    else if (t < 128) b1s[t - 64] = V1_b[t - 64];
    __syncthreads();
    // phase C: c1 = xnew @ V0^T (registers)
    float c1[2][4] = {};
#pragma unroll 4
    for (int k = 0; k < 64; k += 4) {
      float4 xv[2], wv[4];
#pragma unroll
      for (int i = 0; i < 2; ++i) xv[i] = *(const float4*)&Xsh[ni + 16 * i][k];
#pragma unroll
      for (int j = 0; j < 4; ++j) wv[j] = *(const float4*)&Wa[h4 + j][k];
#pragma unroll
      for (int i = 0; i < 2; ++i)
#pragma unroll
        for (int j = 0; j < 4; ++j)
          c1[i][j] += xv[i].x * wv[j].x + xv[i].y * wv[j].y + xv[i].z * wv[j].z +
                      xv[i].w * wv[j].w;
    }
    __syncthreads();  // phase-C reads of Xsh done
    // x1 = relu(c1 + b0) -> Xsh
#pragma unroll
    for (int i = 0; i < 2; ++i) {
      float4 o;
      o.x = relu_f(c1[i][0] + b0s[h4 + 0]);
      o.y = relu_f(c1[i][1] + b0s[h4 + 1]);
      o.z = relu_f(c1[i][2] + b0s[h4 + 2]);
      o.w = relu_f(c1[i][3] + b0s[h4 + 3]);
      *(float4*)&Xsh[ni + 16 * i][h4] = o;
    }
    __syncthreads();
    // phase D: out = x1 @ V1^T + b1
    float c2[2][4] = {};
#pragma unroll 4
    for (int k = 0; k < 64; k += 4) {
      float4 xv[2], wv[4];
#pragma unroll
      for (int i = 0; i < 2; ++i) xv[i] = *(const float4*)&Xsh[ni + 16 * i][k];
#pragma unroll
      for (int j = 0; j < 4; ++j) wv[j] = *(const float4*)&Wb[h4 + j][k];
#pragma unroll
      for (int i = 0; i < 2; ++i)
#pragma unroll
        for (int j = 0; j < 4; ++j)
          c2[i][j] += xv[i].x * wv[j].x + xv[i].y * wv[j].y + xv[i].z * wv[j].z +
                      xv[i].w * wv[j].w;
    }
#pragma unroll
    for (int i = 0; i < 2; ++i) {
      int nn = n_base + ni + 16 * i;
      if (nn < N) {
        float4 o;
        o.x = c2[i][0] + b1s[h4 + 0];
        o.y = c2[i][1] + b1s[h4 + 1];
        o.z = c2[i][2] + b1s[h4 + 2];
        o.w = c2[i][3] + b1s[h4 + 3];
        *(float4*)&head_out[(size_t)nn * 64 + h4] = o;
      }
    }
  }
}

// ---------------- final edge kernel: bf16 gather + Om@Ra bias + transpose ----------
// He_logits[h][e] = MS[S[e]][h] + MR[R[e]][h] + (Om_e@Ra)[h][e]
__global__ __launch_bounds__(256) void edge_final_kernel(
    const u16* __restrict__ MSb, const u16* __restrict__ MRb,
    const int* __restrict__ S, const int* __restrict__ R,
    const float* __restrict__ Om_e, const float* __restrict__ Ra,
    float* __restrict__ He_out, float* __restrict__ Hel_out, int E) {
  __shared__ float T[64][ST];     // [e][h] gather tile
  __shared__ float pool2[4608];   // OmT[64][36] + RaT[64][36]; later transpose (64*65)
  int t = threadIdx.x;
  int e_base = blockIdx.x * 64;
#pragma unroll
  for (int j = 0; j < 8; ++j) {
    int f = t + 256 * j;  // 2048 = 64h x 32j
    int r = f >> 5, c = f & 31;
    pool2[r * 36 + c] = Om_e[f];
  }
#pragma unroll
  for (int j = 0; j < 8; ++j) {
    int f = t + 256 * j;  // 2048 = 32j x 64e
    int r = f >> 6, c = f & 63;
    int e2 = e_base + c;
    pool2[2304 + c * 36 + r] = (e2 < E) ? Ra[(size_t)r * E + e2] : 0.f;
  }
  // gather MS[S]+MR[R] into T (bf16 rows: 16 h = 2 uint4 per thread per stream)
  {
    int e = t >> 2, q = t & 3;
    int ee = e_base + e;
    int ec = (ee < E) ? ee : 0;
    int s = S[ec], r = R[ec];
    const u16* mp = &MSb[((size_t)s << 6) + q * 16];
    const u16* rp = &MRb[((size_t)r << 6) + q * 16];
    uint4 m0 = *(const uint4*)mp;
    uint4 m1 = *(const uint4*)(mp + 8);
    uint4 r0 = *(const uint4*)rp;
    uint4 r1 = *(const uint4*)(rp + 8);
    float* tp = &T[e][q * 16];
    tp[0] = bf_lo(m0.x) + bf_lo(r0.x);
    tp[1] = bf_hi(m0.x) + bf_hi(r0.x);
    tp[2] = bf_lo(m0.y) + bf_lo(r0.y);
    tp[3] = bf_hi(m0.y) + bf_hi(r0.y);
    tp[4] = bf_lo(m0.z) + bf_lo(r0.z);
    tp[5] = bf_hi(m0.z) + bf_hi(r0.z);
    tp[6] = bf_lo(m0.w) + bf_lo(r0.w);
    tp[7] = bf_hi(m0.w) + bf_hi(r0.w);
    tp[8] = bf_lo(m1.x) + bf_lo(r1.x);
    tp[9] = bf_hi(m1.x) + bf_hi(r1.x);
    tp[10] = bf_lo(m1.y) + bf_lo(r1.y);
    tp[11] = bf_hi(m1.y) + bf_hi(r1.y);
    tp[12] = bf_lo(m1.z) + bf_lo(r1.z);
    tp[13] = bf_hi(m1.z) + bf_hi(r1.z);
    tp[14] = bf_lo(m1.w) + bf_lo(r1.w);
    tp[15] = bf_hi(m1.w) + bf_hi(r1.w);
  }
  __syncthreads();
  int ei = t & 15, h4 = (t >> 4) * 4;
  float acc[4][4] = {};
#pragma unroll 4
  for (int jj = 0; jj < 32; jj += 4) {
    float4 ra[4], om[4];
#pragma unroll
    for (int i = 0; i < 4; ++i)
      ra[i] = *(const float4*)&pool2[2304 + (ei + 16 * i) * 36 + jj];
#pragma unroll
    for (int j = 0; j < 4; ++j) om[j] = *(const float4*)&pool2[(h4 + j) * 36 + jj];
#pragma unroll
    for (int i = 0; i < 4; ++i)
#pragma unroll
      for (int j = 0; j < 4; ++j)
        acc[i][j] += ra[i].x * om[j].x + ra[i].y * om[j].y + ra[i].z * om[j].z +
                     ra[i].w * om[j].w;
  }
  // add gathered MS+MR
#pragma unroll
  for (int i = 0; i < 4; ++i) {
    float4 tv = *(const float4*)&T[ei + 16 * i][h4];
    acc[i][0] += tv.x;
    acc[i][1] += tv.y;
    acc[i][2] += tv.z;
    acc[i][3] += tv.w;
  }
  __syncthreads();  // done reading pool2 (OmT/RaT) and T
  // transpose via pool2 (stride 65 -> conflict-light column reads)
#pragma unroll
  for (int i = 0; i < 4; ++i)
#pragma unroll
    for (int j = 0; j < 4; ++j)
      pool2[(ei + 16 * i) * 65 + h4 + j] = acc[i][j];
  __syncthreads();
  {
    int e4 = (t & 15) * 4, h0 = t >> 4;
#pragma unroll
    for (int rep = 0; rep < 4; ++rep) {
      int h = h0 + 16 * rep;
      float4 v;
      v.x = pool2[(e4 + 0) * 65 + h];
      v.y = pool2[(e4 + 1) * 65 + h];
      v.z = pool2[(e4 + 2) * 65 + h];
      v.w = pool2[(e4 + 3) * 65 + h];
      size_t idx = (size_t)h * E + e_base + e4;
      if (e_base + e4 < E) {
        *(float4*)&Hel_out[idx] = v;
        float4 u = make_float4(relu_f(v.x), relu_f(v.y), relu_f(v.z), relu_f(v.w));
        *(float4*)&He_out[idx] = u;
      }
    }
  }
}

extern "C" void kernel_launch(void* const* d_in, const int* in_sizes, int n_in,
                              void* d_out, int out_size, void* d_ws, size_t ws_size,
                              hipStream_t stream) {
  const int* R = (const int*)d_in[0];
  const int* S = (const int*)d_in[1];
  const int* H = (const int*)d_in[2];
  const float* node_data = (const float*)d_in[3];
  const float* Ra = (const float*)d_in[4];
  const float* W_es = (const float*)d_in[5];
  const float* W_er = (const float*)d_in[6];
  const float* Om_e = (const float*)d_in[7];
  const float* Wn = (const float*)d_in[8];
  const float* Bm = (const float*)d_in[9];
  const float* Om_n = (const float*)d_in[10];
  const float* V0_w = (const float*)d_in[11];
  const float* V0_b = (const float*)d_in[12];
  const float* V1_w = (const float*)d_in[13];
  const float* V1_b = (const float*)d_in[14];
  const int E = in_sizes[0];
  const int N = in_sizes[3] / 64;
  const size_t N64 = (size_t)N * 64;

  float* ws = (float*)d_ws;
  float* Wn_hat = ws;                    // 4096 floats
  float* bias_n = Wn_hat + 4096;         // N64 floats
  float* X0 = bias_n + N64;              // N64 floats
  float* X1p = X0 + N64;                 // N64 floats
  u16* MSb_B = (u16*)(X1p + N64);        // N64 u16 (odd-iter MS; final MS)
  u16* MRb_B = MSb_B + N64;              // N64 u16
  int* row_off = (int*)(MRb_B + N64);    // N+1
  int* cursor = row_off + (N + 1);       // N (doubles as histogram)
  int2* SRs = (int2*)(cursor + N);       // E int2
  int* inv_perm = (int*)(SRs + E);       // E

  float* out = (float*)d_out;
  float* out_x = out;                          // [N][64]
  float* out_He = out + N64;                   // [64][E]
  float* out_Hel = out_He + (size_t)64 * E;    // [64][E]
  u16* bias_sb = (u16*)out_He;   // He region: bf16 sorted-bias scratch during iters
  u16* MSb_A = (u16*)out_Hel;    // Hel region: even-iter MS/MR (dead before final)
  u16* MRb_A = MSb_A + N64;

  int nb_node = (N + 63) / 64;
  int nb_iter = (N + TN - 1) / TN;
  int nb_edge = (E + 63) / 64;
  int nb_flat = (E + 255) / 256;

  hipMemsetAsync(cursor, 0, (size_t)N * sizeof(int), stream);
  wnhat_kernel<<<1, 256, 0, stream>>>(Wn, Wn_hat);
  bias_n_kernel<<<nb_node, 256, 0, stream>>>(node_data, Om_n, bias_n, N);
  hist_kernel<<<nb_flat, 256, 0, stream>>>(H, cursor, E);
  scan_kernel<<<1, 256, 0, stream>>>(cursor, row_off, cursor, N, E);
  scatter_kernel<<<nb_flat, 256, 0, stream>>>(H, S, R, cursor, SRs, inv_perm, E);
  bias_build_kernel<<<nb_edge, 256, 0, stream>>>(Ra, Om_e, inv_perm, bias_sb, E);

  float* Xa = X0;
  float* Xb = X1p;
  const u16* msi = nullptr;
  const u16* mri = nullptr;
  for (int it = 0; it < 8; ++it) {
    u16* mso = (it & 1) ? MSb_B : MSb_A;
    u16* mro = (it & 1) ? MRb_B : MRb_A;
    if (it == 0)
      iter_kernel<1, 0><<<nb_iter, 256, 0, stream>>>(
          Xa, nullptr, nullptr, bias_sb, SRs, row_off, bias_n, Wn_hat, Bm, W_es, W_er,
          V0_w, V0_b, V1_w, V1_b, Xb, mso, mro, out_x, N);
    else if (it < 7)
      iter_kernel<0, 0><<<nb_iter, 256, 0, stream>>>(
          Xa, msi, mri, bias_sb, SRs, row_off, bias_n, Wn_hat, Bm, W_es, W_er,
          V0_w, V0_b, V1_w, V1_b, Xb, mso, mro, out_x, N);
    else
      iter_kernel<0, 1><<<nb_iter, 256, 0, stream>>>(
          Xa, msi, mri, bias_sb, SRs, row_off, bias_n, Wn_hat, Bm, W_es, W_er,
          V0_w, V0_b, V1_w, V1_b, Xb, mso, mro, out_x, N);
    msi = mso;
    mri = mro;
    float* tmp = Xa; Xa = Xb; Xb = tmp;
  }
  // it=7 (odd) wrote MSb_B/MRb_B in ws; He/Hel regions are free to write now.
  edge_final_kernel<<<nb_edge, 256, 0, stream>>>(MSb_B, MRb_B, S, R, Om_e, Ra,
                                                 out_He, out_Hel, E);
}

// Round 14
// 432.411 us; speedup vs baseline: 1.4147x; 1.0087x over previous
//
#include <hip/hip_runtime.h>
#include <math.h>

#define KAPPA 0.9f
#define ST 68   // LDS row stride (64+4); 68%32=4 -> 2-way aliasing (free)
#define TN 32   // nodes per node-kernel tile (625 blocks)

typedef unsigned short u16;

__device__ __forceinline__ float relu_f(float v) { return fmaxf(v, 0.0f); }
__device__ __forceinline__ float bf_lo(unsigned u) { return __uint_as_float(u << 16); }
__device__ __forceinline__ float bf_hi(unsigned u) { return __uint_as_float(u & 0xFFFF0000u); }
__device__ __forceinline__ u16 f2bf(float x) {
  unsigned u = __float_as_uint(x);
  return (u16)((u + 0x7FFFu + ((u >> 16) & 1u)) >> 16);
}
__device__ __forceinline__ unsigned pack2(float a, float b) {
  return (unsigned)f2bf(a) | ((unsigned)f2bf(b) << 16);
}

// ---------------- Wn_hat = KAPPA * Wn / max(||Wn||_F, 1) ----------------
__global__ __launch_bounds__(256) void wnhat_kernel(const float* __restrict__ Wn,
                                                    float* __restrict__ Wn_hat) {
  __shared__ float red[4];
  int t = threadIdx.x;
  float v[16];
  float s = 0.f;
#pragma unroll
  for (int j = 0; j < 16; ++j) { v[j] = Wn[t + 256 * j]; s += v[j] * v[j]; }
#pragma unroll
  for (int off = 32; off > 0; off >>= 1) s += __shfl_down(s, off, 64);
  if ((t & 63) == 0) red[t >> 6] = s;
  __syncthreads();
  float norm = sqrtf(red[0] + red[1] + red[2] + red[3]);
  float scale = KAPPA / fmaxf(norm, 1.0f);
#pragma unroll
  for (int j = 0; j < 16; ++j) Wn_hat[t + 256 * j] = v[j] * scale;
}

// ---------------- bias_n[n][h] = sum_k Om_n[h][k] * node_data[k][n] ----------------
__global__ __launch_bounds__(256) void bias_n_kernel(const float* __restrict__ node_data,
                                                     const float* __restrict__ Om_n,
                                                     float* __restrict__ bias_n, int N) {
  __shared__ float NdT[64][ST];  // [n][k]
  __shared__ float Om[64][ST];   // [h][k]
  int t = threadIdx.x;
  int n_base = blockIdx.x * 64;
#pragma unroll
  for (int j = 0; j < 16; ++j) {
    int f = t + 256 * j;
    int r = f >> 6, c = f & 63;
    float val = (n_base + c < N) ? node_data[(size_t)r * N + n_base + c] : 0.f;
    NdT[c][r] = val;
    Om[r][c] = Om_n[f];
  }
  __syncthreads();
  int ni = t & 15, h4 = (t >> 4) * 4;
  float acc[4][4] = {};
#pragma unroll 4
  for (int k = 0; k < 64; k += 4) {
    float4 a[4], w[4];
#pragma unroll
    for (int i = 0; i < 4; ++i) a[i] = *(const float4*)&NdT[ni + 16 * i][k];
#pragma unroll
    for (int j = 0; j < 4; ++j) w[j] = *(const float4*)&Om[h4 + j][k];
#pragma unroll
    for (int i = 0; i < 4; ++i)
#pragma unroll
      for (int j = 0; j < 4; ++j)
        acc[i][j] += a[i].x * w[j].x + a[i].y * w[j].y + a[i].z * w[j].z + a[i].w * w[j].w;
  }
#pragma unroll
  for (int i = 0; i < 4; ++i) {
    int n = n_base + ni + 16 * i;
    if (n < N) {
      float4 o = make_float4(acc[i][0], acc[i][1], acc[i][2], acc[i][3]);
      *(float4*)&bias_n[(size_t)n * 64 + h4] = o;
    }
  }
}

// ---------------- CSR build: histogram / scan / scatter ----------------
__global__ void hist_kernel(const int* __restrict__ H, int* __restrict__ count, int E) {
  int e = blockIdx.x * 256 + threadIdx.x;
  if (e < E) atomicAdd(&count[H[e]], 1);
}

__global__ __launch_bounds__(256) void scan_kernel(int* count, int* row_off, int* cursor,
                                                   int N, int E) {
  __shared__ int offs[256];
  __shared__ int sums[256];
  int t = threadIdx.x;
  int chunk = (N + 255) / 256;
  int lo = t * chunk, hi = min(lo + chunk, N);
  int s = 0;
  for (int n = lo; n < hi; ++n) s += count[n];
  sums[t] = s;
  __syncthreads();
  if (t == 0) {
    int run = 0;
    for (int i = 0; i < 256; ++i) { offs[i] = run; run += sums[i]; }
  }
  __syncthreads();
  int run = offs[t];
  for (int n = lo; n < hi; ++n) {
    int c = count[n];   // count and cursor may alias: read first
    row_off[n] = run;
    cursor[n] = run;
    run += c;
  }
  if (t == 0) row_off[N] = E;
}

__global__ void scatter_kernel(const int* __restrict__ H, const int* __restrict__ S,
                               const int* __restrict__ R, int* cursor,
                               int2* __restrict__ SRs, int* __restrict__ inv_perm, int E) {
  int e = blockIdx.x * 256 + threadIdx.x;
  if (e < E) {
    int h = H[e];
    int pos = atomicAdd(&cursor[h], 1);
    SRs[pos] = make_int2(S[e], R[e]);
    inv_perm[e] = pos;
  }
}

// ---------------- bias_sb[inv_perm[e]][h] = bf16( sum_j Om_e[h][j] * Ra[j][e] ) -------
__global__ __launch_bounds__(256) void bias_build_kernel(const float* __restrict__ Ra,
                                                         const float* __restrict__ Om_e,
                                                         const int* __restrict__ inv_perm,
                                                         u16* __restrict__ bias_sb, int E) {
  __shared__ float OmT[64][36];  // [h][j]
  __shared__ float RaT[64][36];  // [e][j]
  int t = threadIdx.x;
  int e_base = blockIdx.x * 64;
#pragma unroll
  for (int j = 0; j < 8; ++j) {
    int f = t + 256 * j;  // 2048 = 64h x 32j
    int r = f >> 5, c = f & 31;
    OmT[r][c] = Om_e[f];
  }
#pragma unroll
  for (int j = 0; j < 8; ++j) {
    int f = t + 256 * j;  // 2048 = 32j x 64e
    int r = f >> 6, c = f & 63;
    int ee = e_base + c;
    RaT[c][r] = (ee < E) ? Ra[(size_t)r * E + ee] : 0.f;
  }
  __syncthreads();
  int ei = t & 15, h4 = (t >> 4) * 4;
  float acc[4][4] = {};
#pragma unroll 4
  for (int jj = 0; jj < 32; jj += 4) {
    float4 ra[4], om[4];
#pragma unroll
    for (int i = 0; i < 4; ++i) ra[i] = *(const float4*)&RaT[ei + 16 * i][jj];
#pragma unroll
    for (int j = 0; j < 4; ++j) om[j] = *(const float4*)&OmT[h4 + j][jj];
#pragma unroll
    for (int i = 0; i < 4; ++i)
#pragma unroll
      for (int j = 0; j < 4; ++j)
        acc[i][j] += ra[i].x * om[j].x + ra[i].y * om[j].y + ra[i].z * om[j].z +
                     ra[i].w * om[j].w;
  }
#pragma unroll
  for (int i = 0; i < 4; ++i) {
    int e = e_base + ei + 16 * i;
    if (e < E) {
      int p = inv_perm[e];
      uint2 o;
      o.x = pack2(acc[i][0], acc[i][1]);
      o.y = pack2(acc[i][2], acc[i][3]);
      *(uint2*)&bias_sb[((size_t)p << 6) + h4] = o;
    }
  }
}

// ---------------- high-occupancy aggregation kernel ----------------
// Block: 8 nodes x 4 edge-splits x 8 h-chunks = 256 threads; no weight LDS.
// 8 blocks/CU resident (32 waves) => latency-hiding via TLP; ~2 edges/thread.
template <int FIRST>
__global__ __launch_bounds__(256) void agg_kernel(
    const u16* __restrict__ MSb_in, const u16* __restrict__ MRb_in,
    const u16* __restrict__ bias_sb, const int2* __restrict__ SRs,
    const int* __restrict__ row_off, float* __restrict__ agg, int N) {
  __shared__ float part[4][8][ST];  // [split][node][h]
  int t = threadIdx.x;
  int nl = t >> 5, sp = (t >> 3) & 3, q8 = t & 7;
  int nd = blockIdx.x * 8 + nl;
  float a[8] = {};
  if (nd < N) {
    int r0 = row_off[nd], r1 = row_off[nd + 1];
    for (int p = r0 + sp; p < r1; p += 4) {
      uint4 bv = *(const uint4*)&bias_sb[((size_t)p << 6) + q8 * 8];
      if (FIRST) {
        a[0] += relu_f(bf_lo(bv.x)); a[1] += relu_f(bf_hi(bv.x));
        a[2] += relu_f(bf_lo(bv.y)); a[3] += relu_f(bf_hi(bv.y));
        a[4] += relu_f(bf_lo(bv.z)); a[5] += relu_f(bf_hi(bv.z));
        a[6] += relu_f(bf_lo(bv.w)); a[7] += relu_f(bf_hi(bv.w));
      } else {
        int2 sr = SRs[p];
        uint4 mv = *(const uint4*)&MSb_in[((size_t)sr.x << 6) + q8 * 8];
        uint4 rv = *(const uint4*)&MRb_in[((size_t)sr.y << 6) + q8 * 8];
        a[0] += relu_f(bf_lo(mv.x) + bf_lo(rv.x) + bf_lo(bv.x));
        a[1] += relu_f(bf_hi(mv.x) + bf_hi(rv.x) + bf_hi(bv.x));
        a[2] += relu_f(bf_lo(mv.y) + bf_lo(rv.y) + bf_lo(bv.y));
        a[3] += relu_f(bf_hi(mv.y) + bf_hi(rv.y) + bf_hi(bv.y));
        a[4] += relu_f(bf_lo(mv.z) + bf_lo(rv.z) + bf_lo(bv.z));
        a[5] += relu_f(bf_hi(mv.z) + bf_hi(rv.z) + bf_hi(bv.z));
        a[6] += relu_f(bf_lo(mv.w) + bf_lo(rv.w) + bf_lo(bv.w));
        a[7] += relu_f(bf_hi(mv.w) + bf_hi(rv.w) + bf_hi(bv.w));
      }
    }
  }
  *(float4*)&part[sp][nl][q8 * 8] = make_float4(a[0], a[1], a[2], a[3]);
  *(float4*)&part[sp][nl][q8 * 8 + 4] = make_float4(a[4], a[5], a[6], a[7]);
  __syncthreads();
  if (sp == 0 && nd < N) {
#pragma unroll
    for (int u = 0; u < 2; ++u) {
      float4 s0 = *(const float4*)&part[0][nl][q8 * 8 + 4 * u];
      float4 s1 = *(const float4*)&part[1][nl][q8 * 8 + 4 * u];
      float4 s2 = *(const float4*)&part[2][nl][q8 * 8 + 4 * u];
      float4 s3 = *(const float4*)&part[3][nl][q8 * 8 + 4 * u];
      float4 o = make_float4(s0.x + s1.x + s2.x + s3.x, s0.y + s1.y + s2.y + s3.y,
                             s0.z + s1.z + s2.z + s3.z, s0.w + s1.w + s2.w + s3.w);
      *(float4*)&agg[(size_t)nd * 64 + q8 * 8 + 4 * u] = o;
    }
  }
}

// ---------------- node GEMM kernel (TN=32, weights in LDS) ----------------
// xnew = relu(Wn_hat@X + Bm@agg + bias_n); MS/MR = bf16(Wes/Wer @ xnew).
// FIRST: skip X staging and Wn_hat@X term. LAST: run head; skip Xout write.
template <int FIRST, int LAST>
__global__ __launch_bounds__(256) void node_kernel(
    const float* __restrict__ X, const float* __restrict__ agg,
    const float* __restrict__ bias_n, const float* __restrict__ Wn_hat,
    const float* __restrict__ Bm, const float* __restrict__ W_es,
    const float* __restrict__ W_er, const float* __restrict__ V0_w,
    const float* __restrict__ V0_b, const float* __restrict__ V1_w,
    const float* __restrict__ V1_b, float* __restrict__ Xout,
    u16* __restrict__ MSb_out, u16* __restrict__ MRb_out,
    float* __restrict__ head_out, int N) {
  __shared__ float Wa[64][ST], Wb[64][ST];
  __shared__ float Xsh[TN][ST], Ash[TN][ST];
  __shared__ float b0s[64], b1s[64];
  int t = threadIdx.x;
  int n_base = blockIdx.x * TN;
  // stage phase-A weights
#pragma unroll
  for (int j = 0; j < 16; ++j) {
    int f = t + 256 * j;
    int r = f >> 6, c = f & 63;
    Wa[r][c] = Wn_hat[f];
    Wb[r][c] = Bm[f];
  }
  int n8 = t >> 3;   // node slot 0..31
  int q8 = t & 7;    // 8-h chunk 0..7
  int nd = n_base + n8;
  bool ok = nd < N;
  if (!FIRST) {
    float4 x0 = make_float4(0, 0, 0, 0), x1 = x0;
    if (ok) {
      x0 = *(const float4*)&X[(size_t)nd * 64 + q8 * 8];
      x1 = *(const float4*)&X[(size_t)nd * 64 + q8 * 8 + 4];
    }
    *(float4*)&Xsh[n8][q8 * 8] = x0;
    *(float4*)&Xsh[n8][q8 * 8 + 4] = x1;
  }
  {
    float4 a0 = make_float4(0, 0, 0, 0), a1 = a0;
    if (ok) {
      a0 = *(const float4*)&agg[(size_t)nd * 64 + q8 * 8];
      a1 = *(const float4*)&agg[(size_t)nd * 64 + q8 * 8 + 4];
    }
    *(float4*)&Ash[n8][q8 * 8] = a0;
    *(float4*)&Ash[n8][q8 * 8 + 4] = a1;
  }
  __syncthreads();
  // phase A (fused): acc = Wn_hat@X + Bm@agg ; rows = ni, ni+16; cols = h4..h4+3
  int ni = t & 15, h4 = (t >> 4) * 4;
  float acc[2][4] = {};
#pragma unroll 4
  for (int k = 0; k < 64; k += 4) {
    float4 xv[2], av[2], wv[4], bv[4];
#pragma unroll
    for (int i = 0; i < 2; ++i) {
      if (!FIRST) xv[i] = *(const float4*)&Xsh[ni + 16 * i][k];
      av[i] = *(const float4*)&Ash[ni + 16 * i][k];
    }
#pragma unroll
    for (int j = 0; j < 4; ++j) {
      wv[j] = *(const float4*)&Wa[h4 + j][k];
      bv[j] = *(const float4*)&Wb[h4 + j][k];
    }
#pragma unroll
    for (int i = 0; i < 2; ++i)
#pragma unroll
      for (int j = 0; j < 4; ++j) {
        float v = av[i].x * bv[j].x + av[i].y * bv[j].y + av[i].z * bv[j].z +
                  av[i].w * bv[j].w;
        if (!FIRST)
          v += xv[i].x * wv[j].x + xv[i].y * wv[j].y + xv[i].z * wv[j].z +
               xv[i].w * wv[j].w;
        acc[i][j] += v;
      }
  }
  __syncthreads();  // phase-A reads of Xsh/Ash/Wa/Wb done
  // epilogue A: xnew = relu(acc + bias_n) -> Xsh (and Xout unless LAST)
#pragma unroll
  for (int i = 0; i < 2; ++i) {
    int nn = n_base + ni + 16 * i;
    float4 bb = make_float4(0, 0, 0, 0);
    if (nn < N) bb = *(const float4*)&bias_n[(size_t)nn * 64 + h4];
    float x0 = relu_f(acc[i][0] + bb.x);
    float x1 = relu_f(acc[i][1] + bb.y);
    float x2 = relu_f(acc[i][2] + bb.z);
    float x3 = relu_f(acc[i][3] + bb.w);
    if (!LAST && nn < N)
      *(float4*)&Xout[(size_t)nn * 64 + h4] = make_float4(x0, x1, x2, x3);
    *(float4*)&Xsh[ni + 16 * i][h4] = make_float4(x0, x1, x2, x3);
  }
  // stage phase-B weights (Wa/Wb reads all done at last barrier)
#pragma unroll
  for (int j = 0; j < 16; ++j) {
    int f = t + 256 * j;
    int r = f >> 6, c = f & 63;
    Wa[r][c] = W_es[f];
    Wb[r][c] = W_er[f];
  }
  __syncthreads();
  // phase B: MS = bf16(Wes@xnew), MR = bf16(Wer@xnew)
  {
    float ma[2][4] = {}, ra[2][4] = {};
#pragma unroll 4
    for (int k = 0; k < 64; k += 4) {
      float4 xv[2], ws[4], wr[4];
#pragma unroll
      for (int i = 0; i < 2; ++i) xv[i] = *(const float4*)&Xsh[ni + 16 * i][k];
#pragma unroll
      for (int j = 0; j < 4; ++j) {
        ws[j] = *(const float4*)&Wa[h4 + j][k];
        wr[j] = *(const float4*)&Wb[h4 + j][k];
      }
#pragma unroll
      for (int i = 0; i < 2; ++i)
#pragma unroll
        for (int j = 0; j < 4; ++j) {
          ma[i][j] += xv[i].x * ws[j].x + xv[i].y * ws[j].y + xv[i].z * ws[j].z +
                      xv[i].w * ws[j].w;
          ra[i][j] += xv[i].x * wr[j].x + xv[i].y * wr[j].y + xv[i].z * wr[j].z +
                      xv[i].w * wr[j].w;
        }
    }
#pragma unroll
    for (int i = 0; i < 2; ++i) {
      int nn = n_base + ni + 16 * i;
      if (nn < N) {
        uint2 om, orr;
        om.x = pack2(ma[i][0], ma[i][1]);
        om.y = pack2(ma[i][2], ma[i][3]);
        orr.x = pack2(ra[i][0], ra[i][1]);
        orr.y = pack2(ra[i][2], ra[i][3]);
        *(uint2*)&MSb_out[((size_t)nn << 6) + h4] = om;
        *(uint2*)&MRb_out[((size_t)nn << 6) + h4] = orr;
      }
    }
  }
  if (LAST) {
    __syncthreads();  // phase-B reads of Wa/Wb done
#pragma unroll
    for (int j = 0; j < 16; ++j) {
      int f = t + 256 * j;
      int r = f >> 6, c = f & 63;
      Wa[r][c] = V0_w[f];
      Wb[r][c] = V1_w[f];
    }
    if (t < 64) b0s[t] = V0_b[t];
    else if (t < 128) b1s[t - 64] = V1_b[t - 64];
    __syncthreads();
    // phase C: c1 = xnew @ V0^T (registers)
    float c1[2][4] = {};
#pragma unroll 4
    for (int k = 0; k < 64; k += 4) {
      float4 xv[2], wv[4];
#pragma unroll
      for (int i = 0; i < 2; ++i) xv[i] = *(const float4*)&Xsh[ni + 16 * i][k];
#pragma unroll
      for (int j = 0; j < 4; ++j) wv[j] = *(const float4*)&Wa[h4 + j][k];
#pragma unroll
      for (int i = 0; i < 2; ++i)
#pragma unroll
        for (int j = 0; j < 4; ++j)
          c1[i][j] += xv[i].x * wv[j].x + xv[i].y * wv[j].y + xv[i].z * wv[j].z +
                      xv[i].w * wv[j].w;
    }
    __syncthreads();  // phase-C reads of Xsh done
    // x1 = relu(c1 + b0) -> Xsh
#pragma unroll
    for (int i = 0; i < 2; ++i) {
      float4 o;
      o.x = relu_f(c1[i][0] + b0s[h4 + 0]);
      o.y = relu_f(c1[i][1] + b0s[h4 + 1]);
      o.z = relu_f(c1[i][2] + b0s[h4 + 2]);
      o.w = relu_f(c1[i][3] + b0s[h4 + 3]);
      *(float4*)&Xsh[ni + 16 * i][h4] = o;
    }
    __syncthreads();
    // phase D: out = x1 @ V1^T + b1
    float c2[2][4] = {};
#pragma unroll 4
    for (int k = 0; k < 64; k += 4) {
      float4 xv[2], wv[4];
#pragma unroll
      for (int i = 0; i < 2; ++i) xv[i] = *(const float4*)&Xsh[ni + 16 * i][k];
#pragma unroll
      for (int j = 0; j < 4; ++j) wv[j] = *(const float4*)&Wb[h4 + j][k];
#pragma unroll
      for (int i = 0; i < 2; ++i)
#pragma unroll
        for (int j = 0; j < 4; ++j)
          c2[i][j] += xv[i].x * wv[j].x + xv[i].y * wv[j].y + xv[i].z * wv[j].z +
                      xv[i].w * wv[j].w;
    }
#pragma unroll
    for (int i = 0; i < 2; ++i) {
      int nn = n_base + ni + 16 * i;
      if (nn < N) {
        float4 o;
        o.x = c2[i][0] + b1s[h4 + 0];
        o.y = c2[i][1] + b1s[h4 + 1];
        o.z = c2[i][2] + b1s[h4 + 2];
        o.w = c2[i][3] + b1s[h4 + 3];
        *(float4*)&head_out[(size_t)nn * 64 + h4] = o;
      }
    }
  }
}

// ---------------- final edge kernel: bf16 gather + Om@Ra bias + transpose ----------
// He_logits[h][e] = MS[S[e]][h] + MR[R[e]][h] + (Om_e@Ra)[h][e]
__global__ __launch_bounds__(256) void edge_final_kernel(
    const u16* __restrict__ MSb, const u16* __restrict__ MRb,
    const int* __restrict__ S, const int* __restrict__ R,
    const float* __restrict__ Om_e, const float* __restrict__ Ra,
    float* __restrict__ He_out, float* __restrict__ Hel_out, int E) {
  __shared__ float T[64][ST];     // [e][h] gather tile
  __shared__ float pool2[4608];   // OmT[64][36] + RaT[64][36]; later transpose (64*65)
  int t = threadIdx.x;
  int e_base = blockIdx.x * 64;
#pragma unroll
  for (int j = 0; j < 8; ++j) {
    int f = t + 256 * j;  // 2048 = 64h x 32j
    int r = f >> 5, c = f & 31;
    pool2[r * 36 + c] = Om_e[f];
  }
#pragma unroll
  for (int j = 0; j < 8; ++j) {
    int f = t + 256 * j;  // 2048 = 32j x 64e
    int r = f >> 6, c = f & 63;
    int e2 = e_base + c;
    pool2[2304 + c * 36 + r] = (e2 < E) ? Ra[(size_t)r * E + e2] : 0.f;
  }
  // gather MS[S]+MR[R] into T (bf16 rows: 16 h = 2 uint4 per thread per stream)
  {
    int e = t >> 2, q = t & 3;
    int ee = e_base + e;
    int ec = (ee < E) ? ee : 0;
    int s = S[ec], r = R[ec];
    const u16* mp = &MSb[((size_t)s << 6) + q * 16];
    const u16* rp = &MRb[((size_t)r << 6) + q * 16];
    uint4 m0 = *(const uint4*)mp;
    uint4 m1 = *(const uint4*)(mp + 8);
    uint4 r0 = *(const uint4*)rp;
    uint4 r1 = *(const uint4*)(rp + 8);
    float* tp = &T[e][q * 16];
    tp[0] = bf_lo(m0.x) + bf_lo(r0.x);
    tp[1] = bf_hi(m0.x) + bf_hi(r0.x);
    tp[2] = bf_lo(m0.y) + bf_lo(r0.y);
    tp[3] = bf_hi(m0.y) + bf_hi(r0.y);
    tp[4] = bf_lo(m0.z) + bf_lo(r0.z);
    tp[5] = bf_hi(m0.z) + bf_hi(r0.z);
    tp[6] = bf_lo(m0.w) + bf_lo(r0.w);
    tp[7] = bf_hi(m0.w) + bf_hi(r0.w);
    tp[8] = bf_lo(m1.x) + bf_lo(r1.x);
    tp[9] = bf_hi(m1.x) + bf_hi(r1.x);
    tp[10] = bf_lo(m1.y) + bf_lo(r1.y);
    tp[11] = bf_hi(m1.y) + bf_hi(r1.y);
    tp[12] = bf_lo(m1.z) + bf_lo(r1.z);
    tp[13] = bf_hi(m1.z) + bf_hi(r1.z);
    tp[14] = bf_lo(m1.w) + bf_lo(r1.w);
    tp[15] = bf_hi(m1.w) + bf_hi(r1.w);
  }
  __syncthreads();
  int ei = t & 15, h4 = (t >> 4) * 4;
  float acc[4][4] = {};
#pragma unroll 4
  for (int jj = 0; jj < 32; jj += 4) {
    float4 ra[4], om[4];
#pragma unroll
    for (int i = 0; i < 4; ++i)
      ra[i] = *(const float4*)&pool2[2304 + (ei + 16 * i) * 36 + jj];
#pragma unroll
    for (int j = 0; j < 4; ++j) om[j] = *(const float4*)&pool2[(h4 + j) * 36 + jj];
#pragma unroll
    for (int i = 0; i < 4; ++i)
#pragma unroll
      for (int j = 0; j < 4; ++j)
        acc[i][j] += ra[i].x * om[j].x + ra[i].y * om[j].y + ra[i].z * om[j].z +
                     ra[i].w * om[j].w;
  }
  // add gathered MS+MR
#pragma unroll
  for (int i = 0; i < 4; ++i) {
    float4 tv = *(const float4*)&T[ei + 16 * i][h4];
    acc[i][0] += tv.x;
    acc[i][1] += tv.y;
    acc[i][2] += tv.z;
    acc[i][3] += tv.w;
  }
  __syncthreads();  // done reading pool2 (OmT/RaT) and T
  // transpose via pool2 (stride 65 -> conflict-light column reads)
#pragma unroll
  for (int i = 0; i < 4; ++i)
#pragma unroll
    for (int j = 0; j < 4; ++j)
      pool2[(ei + 16 * i) * 65 + h4 + j] = acc[i][j];
  __syncthreads();
  {
    int e4 = (t & 15) * 4, h0 = t >> 4;
#pragma unroll
    for (int rep = 0; rep < 4; ++rep) {
      int h = h0 + 16 * rep;
      float4 v;
      v.x = pool2[(e4 + 0) * 65 + h];
      v.y = pool2[(e4 + 1) * 65 + h];
      v.z = pool2[(e4 + 2) * 65 + h];
      v.w = pool2[(e4 + 3) * 65 + h];
      size_t idx = (size_t)h * E + e_base + e4;
      if (e_base + e4 < E) {
        *(float4*)&Hel_out[idx] = v;
        float4 u = make_float4(relu_f(v.x), relu_f(v.y), relu_f(v.z), relu_f(v.w));
        *(float4*)&He_out[idx] = u;
      }
    }
  }
}

extern "C" void kernel_launch(void* const* d_in, const int* in_sizes, int n_in,
                              void* d_out, int out_size, void* d_ws, size_t ws_size,
                              hipStream_t stream) {
  const int* R = (const int*)d_in[0];
  const int* S = (const int*)d_in[1];
  const int* H = (const int*)d_in[2];
  const float* node_data = (const float*)d_in[3];
  const float* Ra = (const float*)d_in[4];
  const float* W_es = (const float*)d_in[5];
  const float* W_er = (const float*)d_in[6];
  const float* Om_e = (const float*)d_in[7];
  const float* Wn = (const float*)d_in[8];
  const float* Bm = (const float*)d_in[9];
  const float* Om_n = (const float*)d_in[10];
  const float* V0_w = (const float*)d_in[11];
  const float* V0_b = (const float*)d_in[12];
  const float* V1_w = (const float*)d_in[13];
  const float* V1_b = (const float*)d_in[14];
  const int E = in_sizes[0];
  const int N = in_sizes[3] / 64;
  const size_t N64 = (size_t)N * 64;

  float* ws = (float*)d_ws;
  float* Wn_hat = ws;                    // 4096 floats
  float* bias_n = Wn_hat + 4096;         // N64 floats
  float* X0 = bias_n + N64;              // N64 floats
  float* X1p = X0 + N64;                 // N64 floats
  u16* MSb_B = (u16*)(X1p + N64);        // N64 u16 (odd-iter MS; final MS)
  u16* MRb_B = MSb_B + N64;              // N64 u16
  int* row_off = (int*)(MRb_B + N64);    // N+1
  int* cursor = row_off + (N + 1);       // N (doubles as histogram)
  int2* SRs = (int2*)(cursor + N);       // E int2
  int* inv_perm = (int*)(SRs + E);       // E

  float* out = (float*)d_out;
  float* out_x = out;                          // [N][64]
  float* out_He = out + N64;                   // [64][E]
  float* out_Hel = out_He + (size_t)64 * E;    // [64][E]
  u16* bias_sb = (u16*)out_He;   // He region: bf16 sorted-bias scratch during iters
  u16* MSb_A = (u16*)out_Hel;    // Hel region: even-iter MS/MR (dead before final)
  u16* MRb_A = MSb_A + N64;
  float* aggf = (float*)(MRb_A + N64);   // Hel region: fp32 agg scratch (5.1 MB)

  int nb_node = (N + 63) / 64;
  int nb_iter = (N + TN - 1) / TN;
  int nb_agg = (N + 7) / 8;
  int nb_edge = (E + 63) / 64;
  int nb_flat = (E + 255) / 256;

  hipMemsetAsync(cursor, 0, (size_t)N * sizeof(int), stream);
  wnhat_kernel<<<1, 256, 0, stream>>>(Wn, Wn_hat);
  bias_n_kernel<<<nb_node, 256, 0, stream>>>(node_data, Om_n, bias_n, N);
  hist_kernel<<<nb_flat, 256, 0, stream>>>(H, cursor, E);
  scan_kernel<<<1, 256, 0, stream>>>(cursor, row_off, cursor, N, E);
  scatter_kernel<<<nb_flat, 256, 0, stream>>>(H, S, R, cursor, SRs, inv_perm, E);
  bias_build_kernel<<<nb_edge, 256, 0, stream>>>(Ra, Om_e, inv_perm, bias_sb, E);

  float* Xa = X0;
  float* Xb = X1p;
  const u16* msi = nullptr;
  const u16* mri = nullptr;
  for (int it = 0; it < 8; ++it) {
    u16* mso = (it & 1) ? MSb_B : MSb_A;
    u16* mro = (it & 1) ? MRb_B : MRb_A;
    if (it == 0) {
      agg_kernel<1><<<nb_agg, 256, 0, stream>>>(nullptr, nullptr, bias_sb, SRs,
                                                row_off, aggf, N);
      node_kernel<1, 0><<<nb_iter, 256, 0, stream>>>(
          Xa, aggf, bias_n, Wn_hat, Bm, W_es, W_er, V0_w, V0_b, V1_w, V1_b,
          Xb, mso, mro, out_x, N);
    } else if (it < 7) {
      agg_kernel<0><<<nb_agg, 256, 0, stream>>>(msi, mri, bias_sb, SRs,
                                                row_off, aggf, N);
      node_kernel<0, 0><<<nb_iter, 256, 0, stream>>>(
          Xa, aggf, bias_n, Wn_hat, Bm, W_es, W_er, V0_w, V0_b, V1_w, V1_b,
          Xb, mso, mro, out_x, N);
    } else {
      agg_kernel<0><<<nb_agg, 256, 0, stream>>>(msi, mri, bias_sb, SRs,
                                                row_off, aggf, N);
      node_kernel<0, 1><<<nb_iter, 256, 0, stream>>>(
          Xa, aggf, bias_n, Wn_hat, Bm, W_es, W_er, V0_w, V0_b, V1_w, V1_b,
          Xb, mso, mro, out_x, N);
    }
    msi = mso;
    mri = mro;
    float* tmp = Xa; Xa = Xb; Xb = tmp;
  }
  // it=7 (odd) wrote MSb_B/MRb_B in ws; He/Hel regions are free to write now.
  edge_final_kernel<<<nb_edge, 256, 0, stream>>>(MSb_B, MRb_B, S, R, Om_e, Ra,
                                                 out_He, out_Hel, E);
}

// Round 15
// 430.909 us; speedup vs baseline: 1.4196x; 1.0035x over previous
//
#include <hip/hip_runtime.h>
#include <math.h>

#define KAPPA 0.9f
#define ST 68   // LDS row stride (64+4); 68%32=4 -> 2-way aliasing (free)
#define TN 32   // nodes per node-kernel tile (625 blocks)

typedef unsigned short u16;

__device__ __forceinline__ float relu_f(float v) { return fmaxf(v, 0.0f); }
__device__ __forceinline__ float bf_lo(unsigned u) { return __uint_as_float(u << 16); }
__device__ __forceinline__ float bf_hi(unsigned u) { return __uint_as_float(u & 0xFFFF0000u); }
__device__ __forceinline__ u16 f2bf(float x) {
  unsigned u = __float_as_uint(x);
  return (u16)((u + 0x7FFFu + ((u >> 16) & 1u)) >> 16);
}
__device__ __forceinline__ unsigned pack2(float a, float b) {
  return (unsigned)f2bf(a) | ((unsigned)f2bf(b) << 16);
}

// ---------------- Wn_hat = KAPPA * Wn / max(||Wn||_F, 1) ----------------
__global__ __launch_bounds__(256) void wnhat_kernel(const float* __restrict__ Wn,
                                                    float* __restrict__ Wn_hat) {
  __shared__ float red[4];
  int t = threadIdx.x;
  float v[16];
  float s = 0.f;
#pragma unroll
  for (int j = 0; j < 16; ++j) { v[j] = Wn[t + 256 * j]; s += v[j] * v[j]; }
#pragma unroll
  for (int off = 32; off > 0; off >>= 1) s += __shfl_down(s, off, 64);
  if ((t & 63) == 0) red[t >> 6] = s;
  __syncthreads();
  float norm = sqrtf(red[0] + red[1] + red[2] + red[3]);
  float scale = KAPPA / fmaxf(norm, 1.0f);
#pragma unroll
  for (int j = 0; j < 16; ++j) Wn_hat[t + 256 * j] = v[j] * scale;
}

// ---------------- bias_n[n][h] = sum_k Om_n[h][k] * node_data[k][n] ----------------
__global__ __launch_bounds__(256) void bias_n_kernel(const float* __restrict__ node_data,
                                                     const float* __restrict__ Om_n,
                                                     float* __restrict__ bias_n, int N) {
  __shared__ float NdT[64][ST];  // [n][k]
  __shared__ float Om[64][ST];   // [h][k]
  int t = threadIdx.x;
  int n_base = blockIdx.x * 64;
#pragma unroll
  for (int j = 0; j < 16; ++j) {
    int f = t + 256 * j;
    int r = f >> 6, c = f & 63;
    float val = (n_base + c < N) ? node_data[(size_t)r * N + n_base + c] : 0.f;
    NdT[c][r] = val;
    Om[r][c] = Om_n[f];
  }
  __syncthreads();
  int ni = t & 15, h4 = (t >> 4) * 4;
  float acc[4][4] = {};
#pragma unroll 4
  for (int k = 0; k < 64; k += 4) {
    float4 a[4], w[4];
#pragma unroll
    for (int i = 0; i < 4; ++i) a[i] = *(const float4*)&NdT[ni + 16 * i][k];
#pragma unroll
    for (int j = 0; j < 4; ++j) w[j] = *(const float4*)&Om[h4 + j][k];
#pragma unroll
    for (int i = 0; i < 4; ++i)
#pragma unroll
      for (int j = 0; j < 4; ++j)
        acc[i][j] += a[i].x * w[j].x + a[i].y * w[j].y + a[i].z * w[j].z + a[i].w * w[j].w;
  }
#pragma unroll
  for (int i = 0; i < 4; ++i) {
    int n = n_base + ni + 16 * i;
    if (n < N) {
      float4 o = make_float4(acc[i][0], acc[i][1], acc[i][2], acc[i][3]);
      *(float4*)&bias_n[(size_t)n * 64 + h4] = o;
    }
  }
}

// ---------------- CSR build: histogram / scan / scatter ----------------
__global__ void hist_kernel(const int* __restrict__ H, int* __restrict__ count, int E) {
  int e = blockIdx.x * 256 + threadIdx.x;
  if (e < E) atomicAdd(&count[H[e]], 1);
}

__global__ __launch_bounds__(256) void scan_kernel(int* count, int* row_off, int* cursor,
                                                   int N, int E) {
  __shared__ int offs[256];
  __shared__ int sums[256];
  int t = threadIdx.x;
  int chunk = (N + 255) / 256;
  int lo = t * chunk, hi = min(lo + chunk, N);
  int s = 0;
  for (int n = lo; n < hi; ++n) s += count[n];
  sums[t] = s;
  __syncthreads();
  if (t == 0) {
    int run = 0;
    for (int i = 0; i < 256; ++i) { offs[i] = run; run += sums[i]; }
  }
  __syncthreads();
  int run = offs[t];
  for (int n = lo; n < hi; ++n) {
    int c = count[n];   // count and cursor may alias: read first
    row_off[n] = run;
    cursor[n] = run;
    run += c;
  }
  if (t == 0) row_off[N] = E;
}

__global__ void scatter_kernel(const int* __restrict__ H, const int* __restrict__ S,
                               const int* __restrict__ R, int* cursor,
                               int2* __restrict__ SRs, int* __restrict__ inv_perm, int E) {
  int e = blockIdx.x * 256 + threadIdx.x;
  if (e < E) {
    int h = H[e];
    int pos = atomicAdd(&cursor[h], 1);
    SRs[pos] = make_int2(S[e], R[e]);
    inv_perm[e] = pos;
  }
}

// ---------------- bias_sb[inv_perm[e]][h] = bf16( sum_j Om_e[h][j] * Ra[j][e] ) -------
__global__ __launch_bounds__(256) void bias_build_kernel(const float* __restrict__ Ra,
                                                         const float* __restrict__ Om_e,
                                                         const int* __restrict__ inv_perm,
                                                         u16* __restrict__ bias_sb, int E) {
  __shared__ float OmT[64][36];  // [h][j]
  __shared__ float RaT[64][36];  // [e][j]
  int t = threadIdx.x;
  int e_base = blockIdx.x * 64;
#pragma unroll
  for (int j = 0; j < 8; ++j) {
    int f = t + 256 * j;  // 2048 = 64h x 32j
    int r = f >> 5, c = f & 31;
    OmT[r][c] = Om_e[f];
  }
#pragma unroll
  for (int j = 0; j < 8; ++j) {
    int f = t + 256 * j;  // 2048 = 32j x 64e
    int r = f >> 6, c = f & 63;
    int ee = e_base + c;
    RaT[c][r] = (ee < E) ? Ra[(size_t)r * E + ee] : 0.f;
  }
  __syncthreads();
  int ei = t & 15, h4 = (t >> 4) * 4;
  float acc[4][4] = {};
#pragma unroll 4
  for (int jj = 0; jj < 32; jj += 4) {
    float4 ra[4], om[4];
#pragma unroll
    for (int i = 0; i < 4; ++i) ra[i] = *(const float4*)&RaT[ei + 16 * i][jj];
#pragma unroll
    for (int j = 0; j < 4; ++j) om[j] = *(const float4*)&OmT[h4 + j][jj];
#pragma unroll
    for (int i = 0; i < 4; ++i)
#pragma unroll
      for (int j = 0; j < 4; ++j)
        acc[i][j] += ra[i].x * om[j].x + ra[i].y * om[j].y + ra[i].z * om[j].z +
                     ra[i].w * om[j].w;
  }
#pragma unroll
  for (int i = 0; i < 4; ++i) {
    int e = e_base + ei + 16 * i;
    if (e < E) {
      int p = inv_perm[e];
      uint2 o;
      o.x = pack2(acc[i][0], acc[i][1]);
      o.y = pack2(acc[i][2], acc[i][3]);
      *(uint2*)&bias_sb[((size_t)p << 6) + h4] = o;
    }
  }
}

// ---------------- high-occupancy aggregation kernel (TLP x 2-wide ILP) ----------
// Block: 8 nodes x 4 edge-splits x 8 h-chunks = 256 threads; ~8 blocks/CU resident.
// Each thread owns edges p = r0+sp, r0+sp+4, ... and processes TWO per pipeline step:
// issue {SRs,bias} x2 together, then all 4 MS/MR rows together.
template <int FIRST>
__global__ __launch_bounds__(256) void agg_kernel(
    const u16* __restrict__ MSb_in, const u16* __restrict__ MRb_in,
    const u16* __restrict__ bias_sb, const int2* __restrict__ SRs,
    const int* __restrict__ row_off, float* __restrict__ agg, int N) {
  __shared__ float part[4][8][ST];  // [split][node][h]
  int t = threadIdx.x;
  int nl = t >> 5, sp = (t >> 3) & 3, q8 = t & 7;
  int nd = blockIdx.x * 8 + nl;
  float a[8] = {};
  if (nd < N) {
    int r0 = row_off[nd], r1 = row_off[nd + 1];
    for (int p = r0 + sp; p < r1; p += 8) {
      int p1 = p + 4;
      bool has1 = p1 < r1;
      int pc1 = has1 ? p1 : p;
      uint4 bv0 = *(const uint4*)&bias_sb[((size_t)p << 6) + q8 * 8];
      uint4 bv1 = *(const uint4*)&bias_sb[((size_t)pc1 << 6) + q8 * 8];
      if (FIRST) {
        a[0] += relu_f(bf_lo(bv0.x)); a[1] += relu_f(bf_hi(bv0.x));
        a[2] += relu_f(bf_lo(bv0.y)); a[3] += relu_f(bf_hi(bv0.y));
        a[4] += relu_f(bf_lo(bv0.z)); a[5] += relu_f(bf_hi(bv0.z));
        a[6] += relu_f(bf_lo(bv0.w)); a[7] += relu_f(bf_hi(bv0.w));
        if (has1) {
          a[0] += relu_f(bf_lo(bv1.x)); a[1] += relu_f(bf_hi(bv1.x));
          a[2] += relu_f(bf_lo(bv1.y)); a[3] += relu_f(bf_hi(bv1.y));
          a[4] += relu_f(bf_lo(bv1.z)); a[5] += relu_f(bf_hi(bv1.z));
          a[6] += relu_f(bf_lo(bv1.w)); a[7] += relu_f(bf_hi(bv1.w));
        }
      } else {
        int2 sr0 = SRs[p];
        int2 sr1 = SRs[pc1];
        uint4 mv0 = *(const uint4*)&MSb_in[((size_t)sr0.x << 6) + q8 * 8];
        uint4 rv0 = *(const uint4*)&MRb_in[((size_t)sr0.y << 6) + q8 * 8];
        uint4 mv1 = *(const uint4*)&MSb_in[((size_t)sr1.x << 6) + q8 * 8];
        uint4 rv1 = *(const uint4*)&MRb_in[((size_t)sr1.y << 6) + q8 * 8];
        a[0] += relu_f(bf_lo(mv0.x) + bf_lo(rv0.x) + bf_lo(bv0.x));
        a[1] += relu_f(bf_hi(mv0.x) + bf_hi(rv0.x) + bf_hi(bv0.x));
        a[2] += relu_f(bf_lo(mv0.y) + bf_lo(rv0.y) + bf_lo(bv0.y));
        a[3] += relu_f(bf_hi(mv0.y) + bf_hi(rv0.y) + bf_hi(bv0.y));
        a[4] += relu_f(bf_lo(mv0.z) + bf_lo(rv0.z) + bf_lo(bv0.z));
        a[5] += relu_f(bf_hi(mv0.z) + bf_hi(rv0.z) + bf_hi(bv0.z));
        a[6] += relu_f(bf_lo(mv0.w) + bf_lo(rv0.w) + bf_lo(bv0.w));
        a[7] += relu_f(bf_hi(mv0.w) + bf_hi(rv0.w) + bf_hi(bv0.w));
        if (has1) {
          a[0] += relu_f(bf_lo(mv1.x) + bf_lo(rv1.x) + bf_lo(bv1.x));
          a[1] += relu_f(bf_hi(mv1.x) + bf_hi(rv1.x) + bf_hi(bv1.x));
          a[2] += relu_f(bf_lo(mv1.y) + bf_lo(rv1.y) + bf_lo(bv1.y));
          a[3] += relu_f(bf_hi(mv1.y) + bf_hi(rv1.y) + bf_hi(bv1.y));
          a[4] += relu_f(bf_lo(mv1.z) + bf_lo(rv1.z) + bf_lo(bv1.z));
          a[5] += relu_f(bf_hi(mv1.z) + bf_hi(rv1.z) + bf_hi(bv1.z));
          a[6] += relu_f(bf_lo(mv1.w) + bf_lo(rv1.w) + bf_lo(bv1.w));
          a[7] += relu_f(bf_hi(mv1.w) + bf_hi(rv1.w) + bf_hi(bv1.w));
        }
      }
    }
  }
  *(float4*)&part[sp][nl][q8 * 8] = make_float4(a[0], a[1], a[2], a[3]);
  *(float4*)&part[sp][nl][q8 * 8 + 4] = make_float4(a[4], a[5], a[6], a[7]);
  __syncthreads();
  if (sp == 0 && nd < N) {
#pragma unroll
    for (int u = 0; u < 2; ++u) {
      float4 s0 = *(const float4*)&part[0][nl][q8 * 8 + 4 * u];
      float4 s1 = *(const float4*)&part[1][nl][q8 * 8 + 4 * u];
      float4 s2 = *(const float4*)&part[2][nl][q8 * 8 + 4 * u];
      float4 s3 = *(const float4*)&part[3][nl][q8 * 8 + 4 * u];
      float4 o = make_float4(s0.x + s1.x + s2.x + s3.x, s0.y + s1.y + s2.y + s3.y,
                             s0.z + s1.z + s2.z + s3.z, s0.w + s1.w + s2.w + s3.w);
      *(float4*)&agg[(size_t)nd * 64 + q8 * 8 + 4 * u] = o;
    }
  }
}

// ---------------- node GEMM kernel (TN=32, weights in LDS) ----------------
// xnew = relu(Wn_hat@X + Bm@agg + bias_n); MS/MR = bf16(Wes/Wer @ xnew).
// FIRST: skip X staging and Wn_hat@X term. LAST: run head; skip Xout write.
template <int FIRST, int LAST>
__global__ __launch_bounds__(256) void node_kernel(
    const float* __restrict__ X, const float* __restrict__ agg,
    const float* __restrict__ bias_n, const float* __restrict__ Wn_hat,
    const float* __restrict__ Bm, const float* __restrict__ W_es,
    const float* __restrict__ W_er, const float* __restrict__ V0_w,
    const float* __restrict__ V0_b, const float* __restrict__ V1_w,
    const float* __restrict__ V1_b, float* __restrict__ Xout,
    u16* __restrict__ MSb_out, u16* __restrict__ MRb_out,
    float* __restrict__ head_out, int N) {
  __shared__ float Wa[64][ST], Wb[64][ST];
  __shared__ float Xsh[TN][ST], Ash[TN][ST];
  __shared__ float b0s[64], b1s[64];
  int t = threadIdx.x;
  int n_base = blockIdx.x * TN;
  // stage phase-A weights
#pragma unroll
  for (int j = 0; j < 16; ++j) {
    int f = t + 256 * j;
    int r = f >> 6, c = f & 63;
    Wa[r][c] = Wn_hat[f];
    Wb[r][c] = Bm[f];
  }
  int n8 = t >> 3;   // node slot 0..31
  int q8 = t & 7;    // 8-h chunk 0..7
  int nd = n_base + n8;
  bool ok = nd < N;
  if (!FIRST) {
    float4 x0 = make_float4(0, 0, 0, 0), x1 = x0;
    if (ok) {
      x0 = *(const float4*)&X[(size_t)nd * 64 + q8 * 8];
      x1 = *(const float4*)&X[(size_t)nd * 64 + q8 * 8 + 4];
    }
    *(float4*)&Xsh[n8][q8 * 8] = x0;
    *(float4*)&Xsh[n8][q8 * 8 + 4] = x1;
  }
  {
    float4 a0 = make_float4(0, 0, 0, 0), a1 = a0;
    if (ok) {
      a0 = *(const float4*)&agg[(size_t)nd * 64 + q8 * 8];
      a1 = *(const float4*)&agg[(size_t)nd * 64 + q8 * 8 + 4];
    }
    *(float4*)&Ash[n8][q8 * 8] = a0;
    *(float4*)&Ash[n8][q8 * 8 + 4] = a1;
  }
  __syncthreads();
  // phase A (fused): acc = Wn_hat@X + Bm@agg ; rows = ni, ni+16; cols = h4..h4+3
  int ni = t & 15, h4 = (t >> 4) * 4;
  float acc[2][4] = {};
#pragma unroll 4
  for (int k = 0; k < 64; k += 4) {
    float4 xv[2], av[2], wv[4], bv[4];
#pragma unroll
    for (int i = 0; i < 2; ++i) {
      if (!FIRST) xv[i] = *(const float4*)&Xsh[ni + 16 * i][k];
      av[i] = *(const float4*)&Ash[ni + 16 * i][k];
    }
#pragma unroll
    for (int j = 0; j < 4; ++j) {
      wv[j] = *(const float4*)&Wa[h4 + j][k];
      bv[j] = *(const float4*)&Wb[h4 + j][k];
    }
#pragma unroll
    for (int i = 0; i < 2; ++i)
#pragma unroll
      for (int j = 0; j < 4; ++j) {
        float v = av[i].x * bv[j].x + av[i].y * bv[j].y + av[i].z * bv[j].z +
                  av[i].w * bv[j].w;
        if (!FIRST)
          v += xv[i].x * wv[j].x + xv[i].y * wv[j].y + xv[i].z * wv[j].z +
               xv[i].w * wv[j].w;
        acc[i][j] += v;
      }
  }
  __syncthreads();  // phase-A reads of Xsh/Ash/Wa/Wb done
  // epilogue A: xnew = relu(acc + bias_n) -> Xsh (and Xout unless LAST)
#pragma unroll
  for (int i = 0; i < 2; ++i) {
    int nn = n_base + ni + 16 * i;
    float4 bb = make_float4(0, 0, 0, 0);
    if (nn < N) bb = *(const float4*)&bias_n[(size_t)nn * 64 + h4];
    float x0 = relu_f(acc[i][0] + bb.x);
    float x1 = relu_f(acc[i][1] + bb.y);
    float x2 = relu_f(acc[i][2] + bb.z);
    float x3 = relu_f(acc[i][3] + bb.w);
    if (!LAST && nn < N)
      *(float4*)&Xout[(size_t)nn * 64 + h4] = make_float4(x0, x1, x2, x3);
    *(float4*)&Xsh[ni + 16 * i][h4] = make_float4(x0, x1, x2, x3);
  }
  // stage phase-B weights (Wa/Wb reads all done at last barrier)
#pragma unroll
  for (int j = 0; j < 16; ++j) {
    int f = t + 256 * j;
    int r = f >> 6, c = f & 63;
    Wa[r][c] = W_es[f];
    Wb[r][c] = W_er[f];
  }
  __syncthreads();
  // phase B: MS = bf16(Wes@xnew), MR = bf16(Wer@xnew)
  {
    float ma[2][4] = {}, ra[2][4] = {};
#pragma unroll 4
    for (int k = 0; k < 64; k += 4) {
      float4 xv[2], ws[4], wr[4];
#pragma unroll
      for (int i = 0; i < 2; ++i) xv[i] = *(const float4*)&Xsh[ni + 16 * i][k];
#pragma unroll
      for (int j = 0; j < 4; ++j) {
        ws[j] = *(const float4*)&Wa[h4 + j][k];
        wr[j] = *(const float4*)&Wb[h4 + j][k];
      }
#pragma unroll
      for (int i = 0; i < 2; ++i)
#pragma unroll
        for (int j = 0; j < 4; ++j) {
          ma[i][j] += xv[i].x * ws[j].x + xv[i].y * ws[j].y + xv[i].z * ws[j].z +
                      xv[i].w * ws[j].w;
          ra[i][j] += xv[i].x * wr[j].x + xv[i].y * wr[j].y + xv[i].z * wr[j].z +
                      xv[i].w * wr[j].w;
        }
    }
#pragma unroll
    for (int i = 0; i < 2; ++i) {
      int nn = n_base + ni + 16 * i;
      if (nn < N) {
        uint2 om, orr;
        om.x = pack2(ma[i][0], ma[i][1]);
        om.y = pack2(ma[i][2], ma[i][3]);
        orr.x = pack2(ra[i][0], ra[i][1]);
        orr.y = pack2(ra[i][2], ra[i][3]);
        *(uint2*)&MSb_out[((size_t)nn << 6) + h4] = om;
        *(uint2*)&MRb_out[((size_t)nn << 6) + h4] = orr;
      }
    }
  }
  if (LAST) {
    __syncthreads();  // phase-B reads of Wa/Wb done
#pragma unroll
    for (int j = 0; j < 16; ++j) {
      int f = t + 256 * j;
      int r = f >> 6, c = f & 63;
      Wa[r][c] = V0_w[f];
      Wb[r][c] = V1_w[f];
    }
    if (t < 64) b0s[t] = V0_b[t];
    else if (t < 128) b1s[t - 64] = V1_b[t - 64];
    __syncthreads();
    // phase C: c1 = xnew @ V0^T (registers)
    float c1[2][4] = {};
#pragma unroll 4
    for (int k = 0; k < 64; k += 4) {
      float4 xv[2], wv[4];
#pragma unroll
      for (int i = 0; i < 2; ++i) xv[i] = *(const float4*)&Xsh[ni + 16 * i][k];
#pragma unroll
      for (int j = 0; j < 4; ++j) wv[j] = *(const float4*)&Wa[h4 + j][k];
#pragma unroll
      for (int i = 0; i < 2; ++i)
#pragma unroll
        for (int j = 0; j < 4; ++j)
          c1[i][j] += xv[i].x * wv[j].x + xv[i].y * wv[j].y + xv[i].z * wv[j].z +
                      xv[i].w * wv[j].w;
    }
    __syncthreads();  // phase-C reads of Xsh done
    // x1 = relu(c1 + b0) -> Xsh
#pragma unroll
    for (int i = 0; i < 2; ++i) {
      float4 o;
      o.x = relu_f(c1[i][0] + b0s[h4 + 0]);
      o.y = relu_f(c1[i][1] + b0s[h4 + 1]);
      o.z = relu_f(c1[i][2] + b0s[h4 + 2]);
      o.w = relu_f(c1[i][3] + b0s[h4 + 3]);
      *(float4*)&Xsh[ni + 16 * i][h4] = o;
    }
    __syncthreads();
    // phase D: out = x1 @ V1^T + b1
    float c2[2][4] = {};
#pragma unroll 4
    for (int k = 0; k < 64; k += 4) {
      float4 xv[2], wv[4];
#pragma unroll
      for (int i = 0; i < 2; ++i) xv[i] = *(const float4*)&Xsh[ni + 16 * i][k];
#pragma unroll
      for (int j = 0; j < 4; ++j) wv[j] = *(const float4*)&Wb[h4 + j][k];
#pragma unroll
      for (int i = 0; i < 2; ++i)
#pragma unroll
        for (int j = 0; j < 4; ++j)
          c2[i][j] += xv[i].x * wv[j].x + xv[i].y * wv[j].y + xv[i].z * wv[j].z +
                      xv[i].w * wv[j].w;
    }
#pragma unroll
    for (int i = 0; i < 2; ++i) {
      int nn = n_base + ni + 16 * i;
      if (nn < N) {
        float4 o;
        o.x = c2[i][0] + b1s[h4 + 0];
        o.y = c2[i][1] + b1s[h4 + 1];
        o.z = c2[i][2] + b1s[h4 + 2];
        o.w = c2[i][3] + b1s[h4 + 3];
        *(float4*)&head_out[(size_t)nn * 64 + h4] = o;
      }
    }
  }
}

// ---------------- final edge kernel: bf16 gather + Om@Ra bias + transpose ----------
// He_logits[h][e] = MS[S[e]][h] + MR[R[e]][h] + (Om_e@Ra)[h][e]
__global__ __launch_bounds__(256) void edge_final_kernel(
    const u16* __restrict__ MSb, const u16* __restrict__ MRb,
    const int* __restrict__ S, const int* __restrict__ R,
    const float* __restrict__ Om_e, const float* __restrict__ Ra,
    float* __restrict__ He_out, float* __restrict__ Hel_out, int E) {
  __shared__ float T[64][ST];     // [e][h] gather tile
  __shared__ float pool2[4608];   // OmT[64][36] + RaT[64][36]; later transpose (64*65)
  int t = threadIdx.x;
  int e_base = blockIdx.x * 64;
#pragma unroll
  for (int j = 0; j < 8; ++j) {
    int f = t + 256 * j;  // 2048 = 64h x 32j
    int r = f >> 5, c = f & 31;
    pool2[r * 36 + c] = Om_e[f];
  }
#pragma unroll
  for (int j = 0; j < 8; ++j) {
    int f = t + 256 * j;  // 2048 = 32j x 64e
    int r = f >> 6, c = f & 63;
    int e2 = e_base + c;
    pool2[2304 + c * 36 + r] = (e2 < E) ? Ra[(size_t)r * E + e2] : 0.f;
  }
  // gather MS[S]+MR[R] into T (bf16 rows: 16 h = 2 uint4 per thread per stream)
  {
    int e = t >> 2, q = t & 3;
    int ee = e_base + e;
    int ec = (ee < E) ? ee : 0;
    int s = S[ec], r = R[ec];
    const u16* mp = &MSb[((size_t)s << 6) + q * 16];
    const u16* rp = &MRb[((size_t)r << 6) + q * 16];
    uint4 m0 = *(const uint4*)mp;
    uint4 m1 = *(const uint4*)(mp + 8);
    uint4 r0 = *(const uint4*)rp;
    uint4 r1 = *(const uint4*)(rp + 8);
    float* tp = &T[e][q * 16];
    tp[0] = bf_lo(m0.x) + bf_lo(r0.x);
    tp[1] = bf_hi(m0.x) + bf_hi(r0.x);
    tp[2] = bf_lo(m0.y) + bf_lo(r0.y);
    tp[3] = bf_hi(m0.y) + bf_hi(r0.y);
    tp[4] = bf_lo(m0.z) + bf_lo(r0.z);
    tp[5] = bf_hi(m0.z) + bf_hi(r0.z);
    tp[6] = bf_lo(m0.w) + bf_lo(r0.w);
    tp[7] = bf_hi(m0.w) + bf_hi(r0.w);
    tp[8] = bf_lo(m1.x) + bf_lo(r1.x);
    tp[9] = bf_hi(m1.x) + bf_hi(r1.x);
    tp[10] = bf_lo(m1.y) + bf_lo(r1.y);
    tp[11] = bf_hi(m1.y) + bf_hi(r1.y);
    tp[12] = bf_lo(m1.z) + bf_lo(r1.z);
    tp[13] = bf_hi(m1.z) + bf_hi(r1.z);
    tp[14] = bf_lo(m1.w) + bf_lo(r1.w);
    tp[15] = bf_hi(m1.w) + bf_hi(r1.w);
  }
  __syncthreads();
  int ei = t & 15, h4 = (t >> 4) * 4;
  float acc[4][4] = {};
#pragma unroll 4
  for (int jj = 0; jj < 32; jj += 4) {
    float4 ra[4], om[4];
#pragma unroll
    for (int i = 0; i < 4; ++i)
      ra[i] = *(const float4*)&pool2[2304 + (ei + 16 * i) * 36 + jj];
#pragma unroll
    for (int j = 0; j < 4; ++j) om[j] = *(const float4*)&pool2[(h4 + j) * 36 + jj];
#pragma unroll
    for (int i = 0; i < 4; ++i)
#pragma unroll
      for (int j = 0; j < 4; ++j)
        acc[i][j] += ra[i].x * om[j].x + ra[i].y * om[j].y + ra[i].z * om[j].z +
                     ra[i].w * om[j].w;
  }
  // add gathered MS+MR
#pragma unroll
  for (int i = 0; i < 4; ++i) {
    float4 tv = *(const float4*)&T[ei + 16 * i][h4];
    acc[i][0] += tv.x;
    acc[i][1] += tv.y;
    acc[i][2] += tv.z;
    acc[i][3] += tv.w;
  }
  __syncthreads();  // done reading pool2 (OmT/RaT) and T
  // transpose via pool2 (stride 65 -> conflict-light column reads)
#pragma unroll
  for (int i = 0; i < 4; ++i)
#pragma unroll
    for (int j = 0; j < 4; ++j)
      pool2[(ei + 16 * i) * 65 + h4 + j] = acc[i][j];
  __syncthreads();
  {
    int e4 = (t & 15) * 4, h0 = t >> 4;
#pragma unroll
    for (int rep = 0; rep < 4; ++rep) {
      int h = h0 + 16 * rep;
      float4 v;
      v.x = pool2[(e4 + 0) * 65 + h];
      v.y = pool2[(e4 + 1) * 65 + h];
      v.z = pool2[(e4 + 2) * 65 + h];
      v.w = pool2[(e4 + 3) * 65 + h];
      size_t idx = (size_t)h * E + e_base + e4;
      if (e_base + e4 < E) {
        *(float4*)&Hel_out[idx] = v;
        float4 u = make_float4(relu_f(v.x), relu_f(v.y), relu_f(v.z), relu_f(v.w));
        *(float4*)&He_out[idx] = u;
      }
    }
  }
}

extern "C" void kernel_launch(void* const* d_in, const int* in_sizes, int n_in,
                              void* d_out, int out_size, void* d_ws, size_t ws_size,
                              hipStream_t stream) {
  const int* R = (const int*)d_in[0];
  const int* S = (const int*)d_in[1];
  const int* H = (const int*)d_in[2];
  const float* node_data = (const float*)d_in[3];
  const float* Ra = (const float*)d_in[4];
  const float* W_es = (const float*)d_in[5];
  const float* W_er = (const float*)d_in[6];
  const float* Om_e = (const float*)d_in[7];
  const float* Wn = (const float*)d_in[8];
  const float* Bm = (const float*)d_in[9];
  const float* Om_n = (const float*)d_in[10];
  const float* V0_w = (const float*)d_in[11];
  const float* V0_b = (const float*)d_in[12];
  const float* V1_w = (const float*)d_in[13];
  const float* V1_b = (const float*)d_in[14];
  const int E = in_sizes[0];
  const int N = in_sizes[3] / 64;
  const size_t N64 = (size_t)N * 64;

  float* ws = (float*)d_ws;
  float* Wn_hat = ws;                    // 4096 floats
  float* bias_n = Wn_hat + 4096;         // N64 floats
  float* X0 = bias_n + N64;              // N64 floats
  float* X1p = X0 + N64;                 // N64 floats
  u16* MSb_B = (u16*)(X1p + N64);        // N64 u16 (odd-iter MS; final MS)
  u16* MRb_B = MSb_B + N64;              // N64 u16
  int* row_off = (int*)(MRb_B + N64);    // N+1
  int* cursor = row_off + (N + 1);       // N (doubles as histogram)
  int2* SRs = (int2*)(cursor + N);       // E int2
  int* inv_perm = (int*)(SRs + E);       // E

  float* out = (float*)d_out;
  float* out_x = out;                          // [N][64]
  float* out_He = out + N64;                   // [64][E]
  float* out_Hel = out_He + (size_t)64 * E;    // [64][E]
  u16* bias_sb = (u16*)out_He;   // He region: bf16 sorted-bias scratch during iters
  u16* MSb_A = (u16*)out_Hel;    // Hel region: even-iter MS/MR (dead before final)
  u16* MRb_A = MSb_A + N64;
  float* aggf = (float*)(MRb_A + N64);   // Hel region: fp32 agg scratch (5.1 MB)

  int nb_node = (N + 63) / 64;
  int nb_iter = (N + TN - 1) / TN;
  int nb_agg = (N + 7) / 8;
  int nb_edge = (E + 63) / 64;
  int nb_flat = (E + 255) / 256;

  hipMemsetAsync(cursor, 0, (size_t)N * sizeof(int), stream);
  wnhat_kernel<<<1, 256, 0, stream>>>(Wn, Wn_hat);
  bias_n_kernel<<<nb_node, 256, 0, stream>>>(node_data, Om_n, bias_n, N);
  hist_kernel<<<nb_flat, 256, 0, stream>>>(H, cursor, E);
  scan_kernel<<<1, 256, 0, stream>>>(cursor, row_off, cursor, N, E);
  scatter_kernel<<<nb_flat, 256, 0, stream>>>(H, S, R, cursor, SRs, inv_perm, E);
  bias_build_kernel<<<nb_edge, 256, 0, stream>>>(Ra, Om_e, inv_perm, bias_sb, E);

  float* Xa = X0;
  float* Xb = X1p;
  const u16* msi = nullptr;
  const u16* mri = nullptr;
  for (int it = 0; it < 8; ++it) {
    u16* mso = (it & 1) ? MSb_B : MSb_A;
    u16* mro = (it & 1) ? MRb_B : MRb_A;
    if (it == 0) {
      agg_kernel<1><<<nb_agg, 256, 0, stream>>>(nullptr, nullptr, bias_sb, SRs,
                                                row_off, aggf, N);
      node_kernel<1, 0><<<nb_iter, 256, 0, stream>>>(
          Xa, aggf, bias_n, Wn_hat, Bm, W_es, W_er, V0_w, V0_b, V1_w, V1_b,
          Xb, mso, mro, out_x, N);
    } else if (it < 7) {
      agg_kernel<0><<<nb_agg, 256, 0, stream>>>(msi, mri, bias_sb, SRs,
                                                row_off, aggf, N);
      node_kernel<0, 0><<<nb_iter, 256, 0, stream>>>(
          Xa, aggf, bias_n, Wn_hat, Bm, W_es, W_er, V0_w, V0_b, V1_w, V1_b,
          Xb, mso, mro, out_x, N);
    } else {
      agg_kernel<0><<<nb_agg, 256, 0, stream>>>(msi, mri, bias_sb, SRs,
                                                row_off, aggf, N);
      node_kernel<0, 1><<<nb_iter, 256, 0, stream>>>(
          Xa, aggf, bias_n, Wn_hat, Bm, W_es, W_er, V0_w, V0_b, V1_w, V1_b,
          Xb, mso, mro, out_x, N);
    }
    msi = mso;
    mri = mro;
    float* tmp = Xa; Xa = Xb; Xb = tmp;
  }
  // it=7 (odd) wrote MSb_B/MRb_B in ws; He/Hel regions are free to write now.
  edge_final_kernel<<<nb_edge, 256, 0, stream>>>(MSb_B, MRb_B, S, R, Om_e, Ra,
                                                 out_He, out_Hel, E);
}